// Round 12
// baseline (303.642 us; speedup 1.0000x reference)
//
#include <hip/hip_runtime.h>
#include <hip/hip_bf16.h>
#include <hip/hip_fp16.h>

#define NNODES 50000
#define NEDGES 600000
#define DIM    128
#define NLAYERS 3
#define NCLS   10
#define NGRAPH 256
#define BN_EPS 1e-5f

#define SCAN_BLK 256
#define NSB ((NNODES + SCAN_BLK - 1) / SCAN_BLK)   // 196 blocks
#define NBINS 128   // key = (snmask<<6) | min(deg,63)

typedef __attribute__((ext_vector_type(8))) short bf16x8;   // 8 bf16 = 4 VGPR
typedef __attribute__((ext_vector_type(4))) float f32x4;

static __device__ __forceinline__ unsigned short f2b(float f) {
    union { __hip_bfloat16 h; unsigned short u; } c;
    c.h = __float2bfloat16(f);
    return c.u;
}
static __device__ __forceinline__ float b2f(short s) {
    return __uint_as_float(((unsigned)(unsigned short)s) << 16);
}
static __device__ __forceinline__ unsigned pack2(float a, float b) {
    return (unsigned)f2b(a) | ((unsigned)f2b(b) << 16);
}

// ---------------- workspace zeroing ----------------
__global__ __launch_bounds__(256) void zero_bufs(int4* __restrict__ a, int na,
                                                 int4* __restrict__ b, int nb) {
    int i = blockIdx.x * 256 + threadIdx.x;
    int4 z = make_int4(0, 0, 0, 0);
    if (i < na) a[i] = z;
    if (i < nb) b[i] = z;
}

// ---------------- CSR build ----------------
__global__ void count_deg(const int* __restrict__ dst, int* __restrict__ deg,
                          int* __restrict__ rank, int E) {
    int e = blockIdx.x * blockDim.x + threadIdx.x;
    if (e < E) rank[e] = atomicAdd(&deg[dst[e]], 1);
}

__global__ __launch_bounds__(SCAN_BLK) void partial_sum(const int* __restrict__ deg,
                                                        int* __restrict__ part, int n) {
    int t = threadIdx.x;
    int i = blockIdx.x * SCAN_BLK + t;
    int v = (i < n) ? deg[i] : 0;
#pragma unroll
    for (int o = 32; o > 0; o >>= 1) v += __shfl_down(v, o, 64);
    __shared__ int s[SCAN_BLK / 64];
    if ((t & 63) == 0) s[t >> 6] = v;
    __syncthreads();
    if (t == 0) {
        int sum = 0;
#pragma unroll
        for (int w = 0; w < SCAN_BLK / 64; ++w) sum += s[w];
        part[blockIdx.x] = sum;
    }
}

__global__ __launch_bounds__(256) void scan_partials(int* __restrict__ part, int nb) {
    __shared__ int s[256];
    int t = threadIdx.x;
    int v = (t < nb) ? part[t] : 0;
    s[t] = v;
    __syncthreads();
    for (int o = 1; o < 256; o <<= 1) {
        int u = (t >= o) ? s[t - o] : 0;
        __syncthreads();
        s[t] += u;
        __syncthreads();
    }
    if (t < nb) part[t] = (t == 0) ? 0 : s[t - 1];
}

__global__ __launch_bounds__(SCAN_BLK) void emit_offsets(const int* __restrict__ deg,
                                                         const int* __restrict__ part,
                                                         int* __restrict__ off, int n) {
    __shared__ int s[SCAN_BLK];
    int t = threadIdx.x;
    int i = blockIdx.x * SCAN_BLK + t;
    int v = (i < n) ? deg[i] : 0;
    s[t] = v;
    __syncthreads();
    for (int o = 1; o < SCAN_BLK; o <<= 1) {
        int u = (t >= o) ? s[t - o] : 0;
        __syncthreads();
        s[t] += u;
        __syncthreads();
    }
    if (i < n) off[i] = part[blockIdx.x] + s[t] - v;
}

// pure scatter, no atomics: 4B per edge (low16 src, high16 f16 weight)
__global__ void place_csr(const int* __restrict__ src, const int* __restrict__ dst,
                          const float* __restrict__ emask,
                          const int* __restrict__ off, const int* __restrict__ rank,
                          unsigned* __restrict__ csr4, int E) {
    int e = blockIdx.x * blockDim.x + threadIdx.x;
    if (e < E) {
        int d = dst[e];
        unsigned wbits = (unsigned)__half_as_ushort(__float2half(emask[e]));
        csr4[off[d] + rank[e]] = (unsigned)src[e] | (wbits << 16);
    }
}

// ---------------- (snmask, degree)-keyed permutation: contention-free counting sort ----------------
// key = (snmask<<6)|min(deg,63): non-sn nodes grouped (gather0 skips them entirely),
// degree-matched quarter-waves within each class.

static __device__ __forceinline__ int sort_key(int sn, int dg) {
    int b = dg > 63 ? 63 : dg;
    return (sn ? 64 : 0) | b;
}

__global__ __launch_bounds__(256) void hist_block(const int* __restrict__ deg,
                                                  const int* __restrict__ snmask,
                                                  int* __restrict__ blockHist, int n) {
    __shared__ int h[NBINS];
    int t = threadIdx.x;
    if (t < NBINS) h[t] = 0;
    __syncthreads();
    int i = blockIdx.x * 256 + t;
    if (i < n) atomicAdd(&h[sort_key(snmask[i], deg[i])], 1);   // LDS atomic
    __syncthreads();
    if (t < NBINS) blockHist[t * NSB + blockIdx.x] = h[t];      // bin-major
}

__global__ __launch_bounds__(1024) void scan_matrix(int* __restrict__ m, int total) {
    __shared__ int s[1024];
    int t = threadIdx.x;
    const int CH = (total + 1023) / 1024;   // 25
    int lo = t * CH;
    int hi = lo + CH; if (hi > total) hi = total;
    int sum = 0;
    for (int i = lo; i < hi; ++i) sum += m[i];
    s[t] = sum;
    __syncthreads();
    for (int o = 1; o < 1024; o <<= 1) {
        int v = (t >= o) ? s[t - o] : 0;
        __syncthreads();
        s[t] += v;
        __syncthreads();
    }
    int run = (t == 0) ? 0 : s[t - 1];
    for (int i = lo; i < hi; ++i) {
        int v = m[i]; m[i] = run; run += v;
    }
}

__global__ __launch_bounds__(256) void place_block(const int* __restrict__ deg,
                                                   const int* __restrict__ snmask,
                                                   const int* __restrict__ blockHist,
                                                   int* __restrict__ perm, int n) {
    __shared__ int h[NBINS];
    int t = threadIdx.x;
    if (t < NBINS) h[t] = 0;
    __syncthreads();
    int i = blockIdx.x * 256 + t;
    if (i < n) {
        int b = sort_key(snmask[i], deg[i]);
        int r = atomicAdd(&h[b], 1);   // LDS rank within (block, bin)
        perm[blockHist[b * NSB + blockIdx.x] + r] = i;
    }
}

// ---------------- prep: BN fold, W transpose->bf16, x->bf16 ----------------

__global__ void prep_bn(const float* __restrict__ gamma, const float* __restrict__ beta,
                        const float* __restrict__ mean, const float* __restrict__ var,
                        const float* __restrict__ b1,
                        float* __restrict__ colA, float* __restrict__ colB, int n) {
    int i = blockIdx.x * blockDim.x + threadIdx.x;
    if (i < n) {
        float A = gamma[i] * rsqrtf(var[i] + BN_EPS);
        colA[i] = A;
        colB[i] = beta[i] - mean[i] * A + b1[i] * A;
    }
}

// W[l][k][n] f32  ->  WT[l][n][k] bf16
__global__ void prep_wt(const float* __restrict__ W1, const float* __restrict__ W2,
                        unsigned short* __restrict__ W1T, unsigned short* __restrict__ W2T, int total) {
    int i = blockIdx.x * blockDim.x + threadIdx.x;
    if (i < total) {
        int l  = i / (DIM * DIM);
        int r  = i - l * DIM * DIM;
        int nn = r / DIM;
        int kk = r - nn * DIM;
        int sidx = l * DIM * DIM + kk * DIM + nn;
        W1T[i] = f2b(W1[sidx]);
        W2T[i] = f2b(W2[sidx]);
    }
}

__global__ void conv_x(const float* __restrict__ x, unsigned short* __restrict__ xb, int n4) {
    int i = blockIdx.x * blockDim.x + threadIdx.x;
    if (i < n4) {
        float4 v = ((const float4*)x)[i];
        unsigned lo = pack2(v.x, v.y);
        unsigned hi = pack2(v.z, v.w);
        ((uint2*)xb)[i] = make_uint2(lo, hi);
    }
}

// ---------------- gather0: weighted SimpleConv for SUPERNODES ONLY; copy otherwise ----------------
// perm groups non-sn nodes (dg=0 -> pure row copy) and degree-matches sn nodes.
// csr index loads software-pipelined one chunk ahead.

__global__ __launch_bounds__(256) void gather0(const unsigned short* __restrict__ xb,
                                               const int* __restrict__ off, const int* __restrict__ deg,
                                               const unsigned* __restrict__ csr4,
                                               const int* __restrict__ snmask,
                                               const int* __restrict__ perm,
                                               unsigned short* __restrict__ X, int n) {
    int wave = (blockIdx.x * blockDim.x + threadIdx.x) >> 6;
    int lane = threadIdx.x & 63;
    int q    = lane >> 4;
    int l16  = lane & 15;
    int idx  = wave * 4 + q;
    bool valid = idx < n;
    int node = perm[valid ? idx : (n - 1)];
    int base = off[node];
    bool sn  = valid && snmask[node];
    int dg   = sn ? deg[node] : 0;   // non-supernode: skip gather entirely

    float acc[8];
#pragma unroll
    for (int i = 0; i < 8; ++i) acc[i] = 0.f;

    int nch = dg >> 3;
    unsigned cc[8];
    if (nch > 0) {
#pragma unroll
        for (int u = 0; u < 8; ++u) cc[u] = csr4[base + u];
    }
    for (int c = 0; c < nch; ++c) {
        unsigned ccn[8];
        int pb = base + (c + 1 < nch ? (c + 1) * 8 : 0);   // prefetch next (or dummy)
#pragma unroll
        for (int u = 0; u < 8; ++u) ccn[u] = csr4[pb + u];
        bf16x8 vv[8];
#pragma unroll
        for (int u = 0; u < 8; ++u)
            vv[u] = *(const bf16x8*)&xb[(long)(cc[u] & 0xffffu) * DIM + l16 * 8];
#pragma unroll
        for (int u = 0; u < 8; ++u) {
            float w = __half2float(__ushort_as_half((unsigned short)(cc[u] >> 16)));
#pragma unroll
            for (int i = 0; i < 8; ++i) acc[i] = fmaf(w, b2f(vv[u][i]), acc[i]);
        }
#pragma unroll
        for (int u = 0; u < 8; ++u) cc[u] = ccn[u];
    }
    for (int j = nch * 8; j < dg; ++j) {
        unsigned c = csr4[base + j];
        float w = __half2float(__ushort_as_half((unsigned short)(c >> 16)));
        bf16x8 v = *(const bf16x8*)&xb[(long)(c & 0xffffu) * DIM + l16 * 8];
#pragma unroll
        for (int i = 0; i < 8; ++i) acc[i] = fmaf(w, b2f(v[i]), acc[i]);
    }

    if (valid) {
        bf16x8 res;
        if (sn) {
#pragma unroll
            for (int i = 0; i < 8; ++i) res[i] = (short)f2b(acc[i]);
        } else {
            res = *(const bf16x8*)&xb[(long)node * DIM + l16 * 8];
        }
        *(bf16x8*)&X[(long)node * DIM + l16 * 8] = res;
    }
}

// ---------------- fused GIN layer: gather(LDS) -> Lin1+BN+ReLU -> Lin2+ReLU ----------------
// 512 threads = 8 waves, 64 dealt rows/block; single LDS buffer (17.4KB) reused across
// phases with barriers; csr index loads pipelined one chunk ahead.
#define HPITCH 136   // bf16 elems; 272B rows: 16B-aligned, 2-way LDS aliasing only

__global__ __launch_bounds__(512) void gin_layer(const unsigned short* __restrict__ Xin,
                                                 unsigned short* __restrict__ Xout,
                                                 const int* __restrict__ off, const int* __restrict__ deg,
                                                 const unsigned* __restrict__ csr4,
                                                 const int* __restrict__ perm,
                                                 const unsigned short* __restrict__ W1T,
                                                 const unsigned short* __restrict__ W2T,
                                                 const float* __restrict__ colA, const float* __restrict__ colB,
                                                 const float* __restrict__ b2, int n) {
    __shared__ unsigned short h_s[64 * HPITCH];
    int t    = threadIdx.x;
    int wid  = t >> 6;
    int lane = t & 63;
    int q    = lane >> 4;
    int l16  = lane & 15;
    int lm   = lane & 15;
    int lk   = (lane >> 4) * 8;
    int wr   = wid >> 2;          // 0..1
    int wc   = wid & 3;           // 0..3
    int c0   = wc * 32;
    int nb   = gridDim.x;

    // ---- gather phase: GIN eps=0 agg into h_s (dealt, degree-matched quarter-waves) ----
#pragma unroll
    for (int rnd = 0; rnd < 2; ++rnd) {
        int lrow = wid * 8 + rnd * 4 + q;
        int lg   = lrow >> 2;                       // 0..15
        int idx  = (lg * nb + blockIdx.x) * 4 + q;  // dealt group, sorted-adjacent within
        bool valid = idx < n;
        int node = perm[valid ? idx : (n - 1)];
        int base = off[node];
        int dg   = valid ? deg[node] : 0;

        float acc[8];
        {
            bf16x8 self = *(const bf16x8*)&Xin[(long)node * DIM + l16 * 8];
#pragma unroll
            for (int i = 0; i < 8; ++i) acc[i] = b2f(self[i]);
        }
        int nch = dg >> 3;
        unsigned cc[8];
        if (nch > 0) {
#pragma unroll
            for (int u = 0; u < 8; ++u) cc[u] = csr4[base + u];
        }
        for (int c = 0; c < nch; ++c) {
            unsigned ccn[8];
            int pb = base + (c + 1 < nch ? (c + 1) * 8 : 0);
#pragma unroll
            for (int u = 0; u < 8; ++u) ccn[u] = csr4[pb + u];
            bf16x8 vv[8];
#pragma unroll
            for (int u = 0; u < 8; ++u)
                vv[u] = *(const bf16x8*)&Xin[(long)(cc[u] & 0xffffu) * DIM + l16 * 8];
#pragma unroll
            for (int u = 0; u < 8; ++u)
#pragma unroll
                for (int i = 0; i < 8; ++i) acc[i] += b2f(vv[u][i]);
#pragma unroll
            for (int u = 0; u < 8; ++u) cc[u] = ccn[u];
        }
        for (int j = nch * 8; j < dg; ++j) {
            unsigned e = csr4[base + j];
            bf16x8 v = *(const bf16x8*)&Xin[(long)(e & 0xffffu) * DIM + l16 * 8];
#pragma unroll
            for (int i = 0; i < 8; ++i) acc[i] += b2f(v[i]);
        }
        bf16x8 r;
#pragma unroll
        for (int i = 0; i < 8; ++i) r[i] = valid ? (short)f2b(acc[i]) : (short)0;
        *(bf16x8*)&h_s[lrow * HPITCH + l16 * 8] = r;
    }
    __syncthreads();   // (A) gather writes visible

    // ---- GEMM1: A from h_s, B from global W1T ----
    bf16x8 a[2][4];
#pragma unroll
    for (int rs = 0; rs < 2; ++rs)
#pragma unroll
        for (int ks = 0; ks < 4; ++ks)
            a[rs][ks] = *(const bf16x8*)&h_s[(wr * 32 + rs * 16 + lm) * HPITCH + ks * 32 + lk];

    bf16x8 b1[2][4];
#pragma unroll
    for (int cs = 0; cs < 2; ++cs)
#pragma unroll
        for (int ks = 0; ks < 4; ++ks) {
            int col = c0 + cs * 16 + lm;
            b1[cs][ks] = *(const bf16x8*)&W1T[col * DIM + ks * 32 + lk];
        }
    __syncthreads();   // (B) all A-reads done before epi1 overwrites h_s

    f32x4 acc[2][2];
    f32x4 z = {0.f, 0.f, 0.f, 0.f};
#pragma unroll
    for (int rs = 0; rs < 2; ++rs)
#pragma unroll
        for (int cs = 0; cs < 2; ++cs) acc[rs][cs] = z;

#pragma unroll
    for (int ks = 0; ks < 4; ++ks)
#pragma unroll
        for (int rs = 0; rs < 2; ++rs)
#pragma unroll
            for (int cs = 0; cs < 2; ++cs)
                acc[rs][cs] = __builtin_amdgcn_mfma_f32_16x16x32_bf16(a[rs][ks], b1[cs][ks], acc[rs][cs], 0, 0, 0);

    // ---- epilogue 1: affine(BN)+ReLU -> h_s ----
#pragma unroll
    for (int rs = 0; rs < 2; ++rs)
#pragma unroll
        for (int cs = 0; cs < 2; ++cs) {
            int colv = c0 + cs * 16 + lm;
            float cA = colA[colv], cB = colB[colv];
            int rbase = wr * 32 + rs * 16 + (lane >> 4) * 4;
            f32x4 av = acc[rs][cs];
#pragma unroll
            for (int v = 0; v < 4; ++v) {
                float h = fmaxf(fmaf(av[v], cA, cB), 0.f);
                h_s[(rbase + v) * HPITCH + colv] = f2b(h);
            }
        }
    __syncthreads();   // (C) epi1 visible

    // ---- GEMM2: A from h_s, B from global W2T ----
    bf16x8 a2[2][4];
#pragma unroll
    for (int rs = 0; rs < 2; ++rs)
#pragma unroll
        for (int ks = 0; ks < 4; ++ks)
            a2[rs][ks] = *(const bf16x8*)&h_s[(wr * 32 + rs * 16 + lm) * HPITCH + ks * 32 + lk];

    bf16x8 b2f_[2][4];
#pragma unroll
    for (int cs = 0; cs < 2; ++cs)
#pragma unroll
        for (int ks = 0; ks < 4; ++ks) {
            int col = c0 + cs * 16 + lm;
            b2f_[cs][ks] = *(const bf16x8*)&W2T[col * DIM + ks * 32 + lk];
        }

#pragma unroll
    for (int rs = 0; rs < 2; ++rs)
#pragma unroll
        for (int cs = 0; cs < 2; ++cs) acc[rs][cs] = z;

#pragma unroll
    for (int ks = 0; ks < 4; ++ks)
#pragma unroll
        for (int rs = 0; rs < 2; ++rs)
#pragma unroll
            for (int cs = 0; cs < 2; ++cs)
                acc[rs][cs] = __builtin_amdgcn_mfma_f32_16x16x32_bf16(a2[rs][ks], b2f_[cs][ks], acc[rs][cs], 0, 0, 0);

    __syncthreads();   // (D) all a2-reads done before epi2 overwrites h_s

    // ---- epilogue 2: +bias, ReLU -> h_s ----
#pragma unroll
    for (int rs = 0; rs < 2; ++rs)
#pragma unroll
        for (int cs = 0; cs < 2; ++cs) {
            int colv = c0 + cs * 16 + lm;
            float bb = b2[colv];
            int rbase = wr * 32 + rs * 16 + (lane >> 4) * 4;
            f32x4 av = acc[rs][cs];
#pragma unroll
            for (int v = 0; v < 4; ++v) {
                float h = fmaxf(av[v] + bb, 0.f);
                h_s[(rbase + v) * HPITCH + colv] = f2b(h);
            }
        }
    __syncthreads();   // (E) epi2 visible

    // ---- copy-out: row -> dealt idx -> Xout[perm[idx]], 32B per thread ----
    {
        int row = t >> 3;
        int ch  = (t & 7) * 16;
        int idx = ((row >> 2) * nb + blockIdx.x) * 4 + (row & 3);
        if (idx < n) {
            int node = perm[idx];
            *(bf16x8*)&Xout[(long)node * DIM + ch]     = *(const bf16x8*)&h_s[row * HPITCH + ch];
            *(bf16x8*)&Xout[(long)node * DIM + ch + 8] = *(const bf16x8*)&h_s[row * HPITCH + ch + 8];
        }
    }
}

// ---------------- pool (batch sorted -> run-accumulate) ----------------

__global__ __launch_bounds__(128) void pool_kernel(const unsigned short* __restrict__ X,
                                                   const int* __restrict__ batch,
                                                   float* __restrict__ POOL, int n) {
    int c  = threadIdx.x;
    int n0 = blockIdx.x * 128;
    if (n0 >= n) return;
    int n1 = n0 + 128; if (n1 > n) n1 = n;
    int gcur = batch[n0];
    float acc = 0.f;
    for (int i = n0; i < n1; ++i) {
        int g = batch[i];
        if (g != gcur) {
            atomicAdd(&POOL[(long)gcur * DIM + c], acc);
            acc = 0.f; gcur = g;
        }
        acc += __uint_as_float(((unsigned)X[(long)i * DIM + c]) << 16);
    }
    atomicAdd(&POOL[(long)gcur * DIM + c], acc);
}

// ---------------- final head ----------------

__global__ __launch_bounds__(128) void final_mlp(const float* __restrict__ POOL,
                                                 const float* __restrict__ Wf1, const float* __restrict__ bf1,
                                                 const float* __restrict__ Wf2, const float* __restrict__ bf2,
                                                 float* __restrict__ out) {
    int g = blockIdx.x;
    int t = threadIdx.x;
    __shared__ float p[128];
    __shared__ float h[128];
    p[t] = POOL[(long)g * DIM + t];
    __syncthreads();
    float acc = bf1[t];
#pragma unroll 8
    for (int k = 0; k < DIM; ++k) acc = fmaf(p[k], Wf1[k * DIM + t], acc);
    h[t] = fmaxf(acc, 0.f);
    __syncthreads();
    if (t < NCLS) {
        float acc2 = bf2[t];
#pragma unroll 8
        for (int k = 0; k < DIM; ++k) acc2 = fmaf(h[k], Wf2[k * NCLS + t], acc2);
        out[(long)g * NCLS + t] = acc2;
    }
}

// ---------------- launch ----------------

extern "C" void kernel_launch(void* const* d_in, const int* in_sizes, int n_in,
                              void* d_out, int out_size, void* d_ws, size_t ws_size,
                              hipStream_t stream) {
    const float* x      = (const float*)d_in[0];
    const int*   ei     = (const int*)d_in[1];
    const int*   snmask = (const int*)d_in[2];
    const float* emask  = (const float*)d_in[3];
    const int*   batch  = (const int*)d_in[4];
    const float* Ws1    = (const float*)d_in[5];
    const float* bs1    = (const float*)d_in[6];
    const float* gamma  = (const float*)d_in[7];
    const float* beta   = (const float*)d_in[8];
    const float* mean   = (const float*)d_in[9];
    const float* var    = (const float*)d_in[10];
    const float* Ws2    = (const float*)d_in[11];
    const float* bs2    = (const float*)d_in[12];
    const float* Wf1    = (const float*)d_in[13];
    const float* bf1    = (const float*)d_in[14];
    const float* Wf2    = (const float*)d_in[15];
    const float* bf2    = (const float*)d_in[16];
    float* out = (float*)d_out;

    const int* srcp = ei;
    const int* dstp = ei + NEDGES;

    char* ws = (char*)d_ws;
    size_t o = 0;
    auto alloc = [&](size_t bytes) -> void* {
        void* p = ws + o;
        o = (o + bytes + 255) & ~(size_t)255;
        return p;
    };
    unsigned short* XB  = (unsigned short*)alloc((size_t)NNODES * DIM * 2);
    unsigned short* X   = (unsigned short*)alloc((size_t)NNODES * DIM * 2);
    unsigned short* H   = (unsigned short*)alloc((size_t)NNODES * DIM * 2);
    int*   deg     = (int*)alloc((size_t)NNODES * 4);
    int*   off     = (int*)alloc((size_t)NNODES * 4);
    int*   rank    = (int*)alloc((size_t)NEDGES * 4);
    int*   part    = (int*)alloc((size_t)NSB * 4);
    unsigned* csr4 = (unsigned*)alloc((size_t)NEDGES * 4);
    int*   blockHist = (int*)alloc((size_t)NBINS * NSB * 4);
    int*   perm    = (int*)alloc((size_t)NNODES * 4);
    float* colA    = (float*)alloc((size_t)NLAYERS * DIM * 4);
    float* colB    = (float*)alloc((size_t)NLAYERS * DIM * 4);
    unsigned short* W1T = (unsigned short*)alloc((size_t)NLAYERS * DIM * DIM * 2);
    unsigned short* W2T = (unsigned short*)alloc((size_t)NLAYERS * DIM * DIM * 2);
    float* POOL    = (float*)alloc((size_t)NGRAPH * DIM * 4);

    // deg: 12500 int4; POOL: 8192 int4
    zero_bufs<<<(12500 + 255) / 256, 256, 0, stream>>>((int4*)deg, 12500, (int4*)POOL, 8192);

    count_deg<<<(NEDGES + 255) / 256, 256, 0, stream>>>(dstp, deg, rank, NEDGES);
    partial_sum<<<NSB, SCAN_BLK, 0, stream>>>(deg, part, NNODES);
    scan_partials<<<1, 256, 0, stream>>>(part, NSB);
    emit_offsets<<<NSB, SCAN_BLK, 0, stream>>>(deg, part, off, NNODES);
    place_csr<<<(NEDGES + 255) / 256, 256, 0, stream>>>(srcp, dstp, emask, off, rank, csr4, NEDGES);
    hist_block<<<NSB, 256, 0, stream>>>(deg, snmask, blockHist, NNODES);
    scan_matrix<<<1, 1024, 0, stream>>>(blockHist, NBINS * NSB);
    place_block<<<NSB, 256, 0, stream>>>(deg, snmask, blockHist, perm, NNODES);
    prep_bn<<<(NLAYERS * DIM + 255) / 256, 256, 0, stream>>>(gamma, beta, mean, var, bs1, colA, colB, NLAYERS * DIM);
    prep_wt<<<(NLAYERS * DIM * DIM + 255) / 256, 256, 0, stream>>>(Ws1, Ws2, W1T, W2T, NLAYERS * DIM * DIM);
    conv_x<<<(NNODES * DIM / 4 + 255) / 256, 256, 0, stream>>>(x, XB, NNODES * DIM / 4);

    const int nWaves = (NNODES + 3) / 4;
    const int gatherBlocks = (nWaves * 64 + 255) / 256;
    gather0<<<gatherBlocks, 256, 0, stream>>>(XB, off, deg, csr4, snmask, perm, X, NNODES);

    // ping-pong: X -> H -> X -> H
    const unsigned short* bufs[4] = {X, H, X, H};
    const int layerBlocks = (NNODES + 63) / 64;
    for (int l = 0; l < NLAYERS; ++l) {
        gin_layer<<<layerBlocks, 512, 0, stream>>>((const unsigned short*)bufs[l],
                                                   (unsigned short*)bufs[l + 1],
                                                   off, deg, csr4, perm,
                                                   W1T + (size_t)l * DIM * DIM,
                                                   W2T + (size_t)l * DIM * DIM,
                                                   colA + (size_t)l * DIM,
                                                   colB + (size_t)l * DIM,
                                                   bs2 + (size_t)l * DIM, NNODES);
    }

    pool_kernel<<<(NNODES + 127) / 128, 128, 0, stream>>>(H, batch, POOL, NNODES);
    final_mlp<<<NGRAPH, 128, 0, stream>>>(POOL, Wf1, bf1, Wf2, bf2, out);
}

// Round 13
// 287.817 us; speedup vs baseline: 1.0550x; 1.0550x over previous
//
#include <hip/hip_runtime.h>
#include <hip/hip_bf16.h>
#include <hip/hip_fp16.h>

#define NNODES 50000
#define NEDGES 600000
#define DIM    128
#define NLAYERS 3
#define NCLS   10
#define NGRAPH 256
#define BN_EPS 1e-5f

#define SCAN_BLK 256
#define NSB ((NNODES + SCAN_BLK - 1) / SCAN_BLK)   // 196 blocks
#define NBINS 128   // key = (snmask<<6) | min(deg,63)

typedef __attribute__((ext_vector_type(8))) short bf16x8;   // 8 bf16 = 4 VGPR
typedef __attribute__((ext_vector_type(4))) float f32x4;

static __device__ __forceinline__ unsigned short f2b(float f) {
    union { __hip_bfloat16 h; unsigned short u; } c;
    c.h = __float2bfloat16(f);
    return c.u;
}
static __device__ __forceinline__ float b2f(short s) {
    return __uint_as_float(((unsigned)(unsigned short)s) << 16);
}
static __device__ __forceinline__ unsigned pack2(float a, float b) {
    return (unsigned)f2b(a) | ((unsigned)f2b(b) << 16);
}

// ---------------- workspace zeroing ----------------
__global__ __launch_bounds__(256) void zero_bufs(int4* __restrict__ a, int na,
                                                 int4* __restrict__ b, int nb) {
    int i = blockIdx.x * 256 + threadIdx.x;
    int4 z = make_int4(0, 0, 0, 0);
    if (i < na) a[i] = z;
    if (i < nb) b[i] = z;
}

// ---------------- CSR build ----------------
__global__ void count_deg(const int* __restrict__ dst, int* __restrict__ deg,
                          int* __restrict__ rank, int E) {
    int e = blockIdx.x * blockDim.x + threadIdx.x;
    if (e < E) rank[e] = atomicAdd(&deg[dst[e]], 1);
}

__global__ __launch_bounds__(SCAN_BLK) void partial_sum(const int* __restrict__ deg,
                                                        int* __restrict__ part, int n) {
    int t = threadIdx.x;
    int i = blockIdx.x * SCAN_BLK + t;
    int v = (i < n) ? deg[i] : 0;
#pragma unroll
    for (int o = 32; o > 0; o >>= 1) v += __shfl_down(v, o, 64);
    __shared__ int s[SCAN_BLK / 64];
    if ((t & 63) == 0) s[t >> 6] = v;
    __syncthreads();
    if (t == 0) {
        int sum = 0;
#pragma unroll
        for (int w = 0; w < SCAN_BLK / 64; ++w) sum += s[w];
        part[blockIdx.x] = sum;
    }
}

__global__ __launch_bounds__(256) void scan_partials(int* __restrict__ part, int nb) {
    __shared__ int s[256];
    int t = threadIdx.x;
    int v = (t < nb) ? part[t] : 0;
    s[t] = v;
    __syncthreads();
    for (int o = 1; o < 256; o <<= 1) {
        int u = (t >= o) ? s[t - o] : 0;
        __syncthreads();
        s[t] += u;
        __syncthreads();
    }
    if (t < nb) part[t] = (t == 0) ? 0 : s[t - 1];
}

__global__ __launch_bounds__(SCAN_BLK) void emit_offsets(const int* __restrict__ deg,
                                                         const int* __restrict__ part,
                                                         int* __restrict__ off, int n) {
    __shared__ int s[SCAN_BLK];
    int t = threadIdx.x;
    int i = blockIdx.x * SCAN_BLK + t;
    int v = (i < n) ? deg[i] : 0;
    s[t] = v;
    __syncthreads();
    for (int o = 1; o < SCAN_BLK; o <<= 1) {
        int u = (t >= o) ? s[t - o] : 0;
        __syncthreads();
        s[t] += u;
        __syncthreads();
    }
    if (i < n) off[i] = part[blockIdx.x] + s[t] - v;
}

// pure scatter, no atomics: 4B per edge (low16 src, high16 f16 weight)
__global__ void place_csr(const int* __restrict__ src, const int* __restrict__ dst,
                          const float* __restrict__ emask,
                          const int* __restrict__ off, const int* __restrict__ rank,
                          unsigned* __restrict__ csr4, int E) {
    int e = blockIdx.x * blockDim.x + threadIdx.x;
    if (e < E) {
        int d = dst[e];
        unsigned wbits = (unsigned)__half_as_ushort(__float2half(emask[e]));
        csr4[off[d] + rank[e]] = (unsigned)src[e] | (wbits << 16);
    }
}

// ---------------- (snmask, degree)-keyed permutation: contention-free counting sort ----------------

static __device__ __forceinline__ int sort_key(int sn, int dg) {
    int b = dg > 63 ? 63 : dg;
    return (sn ? 64 : 0) | b;
}

__global__ __launch_bounds__(256) void hist_block(const int* __restrict__ deg,
                                                  const int* __restrict__ snmask,
                                                  int* __restrict__ blockHist, int n) {
    __shared__ int h[NBINS];
    int t = threadIdx.x;
    if (t < NBINS) h[t] = 0;
    __syncthreads();
    int i = blockIdx.x * 256 + t;
    if (i < n) atomicAdd(&h[sort_key(snmask[i], deg[i])], 1);   // LDS atomic
    __syncthreads();
    if (t < NBINS) blockHist[t * NSB + blockIdx.x] = h[t];      // bin-major
}

__global__ __launch_bounds__(1024) void scan_matrix(int* __restrict__ m, int total) {
    __shared__ int s[1024];
    int t = threadIdx.x;
    const int CH = (total + 1023) / 1024;   // 25
    int lo = t * CH;
    int hi = lo + CH; if (hi > total) hi = total;
    int sum = 0;
    for (int i = lo; i < hi; ++i) sum += m[i];
    s[t] = sum;
    __syncthreads();
    for (int o = 1; o < 1024; o <<= 1) {
        int v = (t >= o) ? s[t - o] : 0;
        __syncthreads();
        s[t] += v;
        __syncthreads();
    }
    int run = (t == 0) ? 0 : s[t - 1];
    for (int i = lo; i < hi; ++i) {
        int v = m[i]; m[i] = run; run += v;
    }
}

__global__ __launch_bounds__(256) void place_block(const int* __restrict__ deg,
                                                   const int* __restrict__ snmask,
                                                   const int* __restrict__ blockHist,
                                                   int* __restrict__ perm, int n) {
    __shared__ int h[NBINS];
    int t = threadIdx.x;
    if (t < NBINS) h[t] = 0;
    __syncthreads();
    int i = blockIdx.x * 256 + t;
    if (i < n) {
        int b = sort_key(snmask[i], deg[i]);
        int r = atomicAdd(&h[b], 1);   // LDS rank within (block, bin)
        perm[blockHist[b * NSB + blockIdx.x] + r] = i;
    }
}

// ---------------- prep: BN fold, W transpose->bf16, x->bf16 ----------------

__global__ void prep_bn(const float* __restrict__ gamma, const float* __restrict__ beta,
                        const float* __restrict__ mean, const float* __restrict__ var,
                        const float* __restrict__ b1,
                        float* __restrict__ colA, float* __restrict__ colB, int n) {
    int i = blockIdx.x * blockDim.x + threadIdx.x;
    if (i < n) {
        float A = gamma[i] * rsqrtf(var[i] + BN_EPS);
        colA[i] = A;
        colB[i] = beta[i] - mean[i] * A + b1[i] * A;
    }
}

// W[l][k][n] f32  ->  WT[l][n][k] bf16
__global__ void prep_wt(const float* __restrict__ W1, const float* __restrict__ W2,
                        unsigned short* __restrict__ W1T, unsigned short* __restrict__ W2T, int total) {
    int i = blockIdx.x * blockDim.x + threadIdx.x;
    if (i < total) {
        int l  = i / (DIM * DIM);
        int r  = i - l * DIM * DIM;
        int nn = r / DIM;
        int kk = r - nn * DIM;
        int sidx = l * DIM * DIM + kk * DIM + nn;
        W1T[i] = f2b(W1[sidx]);
        W2T[i] = f2b(W2[sidx]);
    }
}

__global__ void conv_x(const float* __restrict__ x, unsigned short* __restrict__ xb, int n4) {
    int i = blockIdx.x * blockDim.x + threadIdx.x;
    if (i < n4) {
        float4 v = ((const float4*)x)[i];
        unsigned lo = pack2(v.x, v.y);
        unsigned hi = pack2(v.z, v.w);
        ((uint2*)xb)[i] = make_uint2(lo, hi);
    }
}

// ---------------- gather0: weighted SimpleConv for SUPERNODES ONLY; copy otherwise ----------------
// round-11 loop structure (plain 8/4/1 unroll, no prefetch) + sn-gate (dg=0 -> copy).

__global__ __launch_bounds__(256) void gather0(const unsigned short* __restrict__ xb,
                                               const int* __restrict__ off, const int* __restrict__ deg,
                                               const unsigned* __restrict__ csr4,
                                               const int* __restrict__ snmask,
                                               const int* __restrict__ perm,
                                               unsigned short* __restrict__ X, int n) {
    int wave = (blockIdx.x * blockDim.x + threadIdx.x) >> 6;
    int lane = threadIdx.x & 63;
    int q    = lane >> 4;
    int l16  = lane & 15;
    int idx  = wave * 4 + q;
    bool valid = idx < n;
    int node = perm[valid ? idx : (n - 1)];
    int base = off[node];
    bool sn  = valid && snmask[node];
    int dg   = sn ? deg[node] : 0;   // non-supernode: skip gather entirely

    float acc[8];
#pragma unroll
    for (int i = 0; i < 8; ++i) acc[i] = 0.f;

    int j = 0;
    for (; j + 8 <= dg; j += 8) {
        unsigned cc[8];
#pragma unroll
        for (int u = 0; u < 8; ++u) cc[u] = csr4[base + j + u];
        bf16x8 vv[8];
#pragma unroll
        for (int u = 0; u < 8; ++u)
            vv[u] = *(const bf16x8*)&xb[(long)(cc[u] & 0xffffu) * DIM + l16 * 8];
#pragma unroll
        for (int u = 0; u < 8; ++u) {
            float w = __half2float(__ushort_as_half((unsigned short)(cc[u] >> 16)));
#pragma unroll
            for (int i = 0; i < 8; ++i) acc[i] = fmaf(w, b2f(vv[u][i]), acc[i]);
        }
    }
    for (; j + 4 <= dg; j += 4) {
        unsigned cc[4];
#pragma unroll
        for (int u = 0; u < 4; ++u) cc[u] = csr4[base + j + u];
        bf16x8 vv[4];
#pragma unroll
        for (int u = 0; u < 4; ++u)
            vv[u] = *(const bf16x8*)&xb[(long)(cc[u] & 0xffffu) * DIM + l16 * 8];
#pragma unroll
        for (int u = 0; u < 4; ++u) {
            float w = __half2float(__ushort_as_half((unsigned short)(cc[u] >> 16)));
#pragma unroll
            for (int i = 0; i < 8; ++i) acc[i] = fmaf(w, b2f(vv[u][i]), acc[i]);
        }
    }
    for (; j < dg; ++j) {
        unsigned c = csr4[base + j];
        float w = __half2float(__ushort_as_half((unsigned short)(c >> 16)));
        bf16x8 v = *(const bf16x8*)&xb[(long)(c & 0xffffu) * DIM + l16 * 8];
#pragma unroll
        for (int i = 0; i < 8; ++i) acc[i] = fmaf(w, b2f(v[i]), acc[i]);
    }

    if (valid) {
        bf16x8 res;
        if (sn) {
#pragma unroll
            for (int i = 0; i < 8; ++i) res[i] = (short)f2b(acc[i]);
        } else {
            res = *(const bf16x8*)&xb[(long)node * DIM + l16 * 8];
        }
        *(bf16x8*)&X[(long)node * DIM + l16 * 8] = res;
    }
}

// ---------------- fused GIN layer (round-11 structure): gather(LDS) -> GEMM1 -> GEMM2 ----------------
// 512 threads = 8 waves, 64 dealt rows/block, dual LDS buffers, W1 fetched before gather.
#define HPITCH 136   // bf16 elems; 272B rows: 16B-aligned, 2-way LDS aliasing only

__global__ __launch_bounds__(512) void gin_layer(const unsigned short* __restrict__ Xin,
                                                 unsigned short* __restrict__ Xout,
                                                 const int* __restrict__ off, const int* __restrict__ deg,
                                                 const unsigned* __restrict__ csr4,
                                                 const int* __restrict__ perm,
                                                 const unsigned short* __restrict__ W1T,
                                                 const unsigned short* __restrict__ W2T,
                                                 const float* __restrict__ colA, const float* __restrict__ colB,
                                                 const float* __restrict__ b2, int n) {
    __shared__ unsigned short h_in[64 * HPITCH];
    __shared__ unsigned short h_t[64 * HPITCH];
    int t    = threadIdx.x;
    int wid  = t >> 6;
    int lane = t & 63;
    int q    = lane >> 4;
    int l16  = lane & 15;
    int lm   = lane & 15;
    int lk   = (lane >> 4) * 8;
    int wr   = wid >> 2;          // 0..1
    int wc   = wid & 3;           // 0..3
    int c0   = wc * 32;
    int nb   = gridDim.x;

    // ---- W1 B-fragments first: weight fetch overlaps gather latency ----
    bf16x8 b1[2][4];
#pragma unroll
    for (int cs = 0; cs < 2; ++cs)
#pragma unroll
        for (int ks = 0; ks < 4; ++ks) {
            int col = c0 + cs * 16 + lm;
            b1[cs][ks] = *(const bf16x8*)&W1T[col * DIM + ks * 32 + lk];
        }

    // ---- gather phase: GIN eps=0 agg into h_in (dealt, degree-matched quarter-waves) ----
#pragma unroll
    for (int rnd = 0; rnd < 2; ++rnd) {
        int lrow = wid * 8 + rnd * 4 + q;
        int lg   = lrow >> 2;                       // 0..15
        int idx  = (lg * nb + blockIdx.x) * 4 + q;  // dealt group, sorted-adjacent within
        bool valid = idx < n;
        int node = perm[valid ? idx : (n - 1)];
        int base = off[node];
        int dg   = valid ? deg[node] : 0;

        float acc[8];
        {
            bf16x8 self = *(const bf16x8*)&Xin[(long)node * DIM + l16 * 8];
#pragma unroll
            for (int i = 0; i < 8; ++i) acc[i] = b2f(self[i]);
        }
        int j = 0;
        for (; j + 8 <= dg; j += 8) {
            unsigned ee[8];
#pragma unroll
            for (int u = 0; u < 8; ++u) ee[u] = csr4[base + j + u];
            bf16x8 vv[8];
#pragma unroll
            for (int u = 0; u < 8; ++u)
                vv[u] = *(const bf16x8*)&Xin[(long)(ee[u] & 0xffffu) * DIM + l16 * 8];
#pragma unroll
            for (int u = 0; u < 8; ++u)
#pragma unroll
                for (int i = 0; i < 8; ++i) acc[i] += b2f(vv[u][i]);
        }
        for (; j + 4 <= dg; j += 4) {
            unsigned ee[4];
#pragma unroll
            for (int u = 0; u < 4; ++u) ee[u] = csr4[base + j + u];
            bf16x8 vv[4];
#pragma unroll
            for (int u = 0; u < 4; ++u)
                vv[u] = *(const bf16x8*)&Xin[(long)(ee[u] & 0xffffu) * DIM + l16 * 8];
#pragma unroll
            for (int u = 0; u < 4; ++u)
#pragma unroll
                for (int i = 0; i < 8; ++i) acc[i] += b2f(vv[u][i]);
        }
        for (; j < dg; ++j) {
            unsigned e = csr4[base + j];
            bf16x8 v = *(const bf16x8*)&Xin[(long)(e & 0xffffu) * DIM + l16 * 8];
#pragma unroll
            for (int i = 0; i < 8; ++i) acc[i] += b2f(v[i]);
        }
        bf16x8 r;
#pragma unroll
        for (int i = 0; i < 8; ++i) r[i] = valid ? (short)f2b(acc[i]) : (short)0;
        *(bf16x8*)&h_in[lrow * HPITCH + l16 * 8] = r;
    }
    __syncthreads();

    // ---- GEMM1 ----
    bf16x8 a[2][4];
#pragma unroll
    for (int rs = 0; rs < 2; ++rs)
#pragma unroll
        for (int ks = 0; ks < 4; ++ks)
            a[rs][ks] = *(const bf16x8*)&h_in[(wr * 32 + rs * 16 + lm) * HPITCH + ks * 32 + lk];

    f32x4 acc[2][2];
    f32x4 z = {0.f, 0.f, 0.f, 0.f};
#pragma unroll
    for (int rs = 0; rs < 2; ++rs)
#pragma unroll
        for (int cs = 0; cs < 2; ++cs) acc[rs][cs] = z;

#pragma unroll
    for (int ks = 0; ks < 4; ++ks)
#pragma unroll
        for (int rs = 0; rs < 2; ++rs)
#pragma unroll
            for (int cs = 0; cs < 2; ++cs)
                acc[rs][cs] = __builtin_amdgcn_mfma_f32_16x16x32_bf16(a[rs][ks], b1[cs][ks], acc[rs][cs], 0, 0, 0);

    // ---- epilogue 1: affine(BN)+ReLU -> h_t ----
#pragma unroll
    for (int rs = 0; rs < 2; ++rs)
#pragma unroll
        for (int cs = 0; cs < 2; ++cs) {
            int colv = c0 + cs * 16 + lm;
            float cA = colA[colv], cB = colB[colv];
            int rbase = wr * 32 + rs * 16 + (lane >> 4) * 4;
            f32x4 av = acc[rs][cs];
#pragma unroll
            for (int v = 0; v < 4; ++v) {
                float h = fmaxf(fmaf(av[v], cA, cB), 0.f);
                h_t[(rbase + v) * HPITCH + colv] = f2b(h);
            }
        }
    __syncthreads();

    // ---- GEMM2 ----
    bf16x8 a2[2][4];
#pragma unroll
    for (int rs = 0; rs < 2; ++rs)
#pragma unroll
        for (int ks = 0; ks < 4; ++ks)
            a2[rs][ks] = *(const bf16x8*)&h_t[(wr * 32 + rs * 16 + lm) * HPITCH + ks * 32 + lk];

    bf16x8 b2f_[2][4];
#pragma unroll
    for (int cs = 0; cs < 2; ++cs)
#pragma unroll
        for (int ks = 0; ks < 4; ++ks) {
            int col = c0 + cs * 16 + lm;
            b2f_[cs][ks] = *(const bf16x8*)&W2T[col * DIM + ks * 32 + lk];
        }

#pragma unroll
    for (int rs = 0; rs < 2; ++rs)
#pragma unroll
        for (int cs = 0; cs < 2; ++cs) acc[rs][cs] = z;

#pragma unroll
    for (int ks = 0; ks < 4; ++ks)
#pragma unroll
        for (int rs = 0; rs < 2; ++rs)
#pragma unroll
            for (int cs = 0; cs < 2; ++cs)
                acc[rs][cs] = __builtin_amdgcn_mfma_f32_16x16x32_bf16(a2[rs][ks], b2f_[cs][ks], acc[rs][cs], 0, 0, 0);

    __syncthreads();

    // ---- epilogue 2: +bias, ReLU -> h_t ----
#pragma unroll
    for (int rs = 0; rs < 2; ++rs)
#pragma unroll
        for (int cs = 0; cs < 2; ++cs) {
            int colv = c0 + cs * 16 + lm;
            float bb = b2[colv];
            int rbase = wr * 32 + rs * 16 + (lane >> 4) * 4;
            f32x4 av = acc[rs][cs];
#pragma unroll
            for (int v = 0; v < 4; ++v) {
                float h = fmaxf(av[v] + bb, 0.f);
                h_t[(rbase + v) * HPITCH + colv] = f2b(h);
            }
        }
    __syncthreads();

    // ---- copy-out: row -> dealt idx -> Xout[perm[idx]], 32B per thread ----
    {
        int row = t >> 3;
        int ch  = (t & 7) * 16;
        int idx = ((row >> 2) * nb + blockIdx.x) * 4 + (row & 3);
        if (idx < n) {
            int node = perm[idx];
            *(bf16x8*)&Xout[(long)node * DIM + ch]     = *(const bf16x8*)&h_t[row * HPITCH + ch];
            *(bf16x8*)&Xout[(long)node * DIM + ch + 8] = *(const bf16x8*)&h_t[row * HPITCH + ch + 8];
        }
    }
}

// ---------------- pool (batch sorted -> run-accumulate) ----------------

__global__ __launch_bounds__(128) void pool_kernel(const unsigned short* __restrict__ X,
                                                   const int* __restrict__ batch,
                                                   float* __restrict__ POOL, int n) {
    int c  = threadIdx.x;
    int n0 = blockIdx.x * 128;
    if (n0 >= n) return;
    int n1 = n0 + 128; if (n1 > n) n1 = n;
    int gcur = batch[n0];
    float acc = 0.f;
    for (int i = n0; i < n1; ++i) {
        int g = batch[i];
        if (g != gcur) {
            atomicAdd(&POOL[(long)gcur * DIM + c], acc);
            acc = 0.f; gcur = g;
        }
        acc += __uint_as_float(((unsigned)X[(long)i * DIM + c]) << 16);
    }
    atomicAdd(&POOL[(long)gcur * DIM + c], acc);
}

// ---------------- final head ----------------

__global__ __launch_bounds__(128) void final_mlp(const float* __restrict__ POOL,
                                                 const float* __restrict__ Wf1, const float* __restrict__ bf1,
                                                 const float* __restrict__ Wf2, const float* __restrict__ bf2,
                                                 float* __restrict__ out) {
    int g = blockIdx.x;
    int t = threadIdx.x;
    __shared__ float p[128];
    __shared__ float h[128];
    p[t] = POOL[(long)g * DIM + t];
    __syncthreads();
    float acc = bf1[t];
#pragma unroll 8
    for (int k = 0; k < DIM; ++k) acc = fmaf(p[k], Wf1[k * DIM + t], acc);
    h[t] = fmaxf(acc, 0.f);
    __syncthreads();
    if (t < NCLS) {
        float acc2 = bf2[t];
#pragma unroll 8
        for (int k = 0; k < DIM; ++k) acc2 = fmaf(h[k], Wf2[k * NCLS + t], acc2);
        out[(long)g * NCLS + t] = acc2;
    }
}

// ---------------- launch ----------------

extern "C" void kernel_launch(void* const* d_in, const int* in_sizes, int n_in,
                              void* d_out, int out_size, void* d_ws, size_t ws_size,
                              hipStream_t stream) {
    const float* x      = (const float*)d_in[0];
    const int*   ei     = (const int*)d_in[1];
    const int*   snmask = (const int*)d_in[2];
    const float* emask  = (const float*)d_in[3];
    const int*   batch  = (const int*)d_in[4];
    const float* Ws1    = (const float*)d_in[5];
    const float* bs1    = (const float*)d_in[6];
    const float* gamma  = (const float*)d_in[7];
    const float* beta   = (const float*)d_in[8];
    const float* mean   = (const float*)d_in[9];
    const float* var    = (const float*)d_in[10];
    const float* Ws2    = (const float*)d_in[11];
    const float* bs2    = (const float*)d_in[12];
    const float* Wf1    = (const float*)d_in[13];
    const float* bf1    = (const float*)d_in[14];
    const float* Wf2    = (const float*)d_in[15];
    const float* bf2    = (const float*)d_in[16];
    float* out = (float*)d_out;

    const int* srcp = ei;
    const int* dstp = ei + NEDGES;

    char* ws = (char*)d_ws;
    size_t o = 0;
    auto alloc = [&](size_t bytes) -> void* {
        void* p = ws + o;
        o = (o + bytes + 255) & ~(size_t)255;
        return p;
    };
    unsigned short* XB  = (unsigned short*)alloc((size_t)NNODES * DIM * 2);
    unsigned short* X   = (unsigned short*)alloc((size_t)NNODES * DIM * 2);
    unsigned short* H   = (unsigned short*)alloc((size_t)NNODES * DIM * 2);
    int*   deg     = (int*)alloc((size_t)NNODES * 4);
    int*   off     = (int*)alloc((size_t)NNODES * 4);
    int*   rank    = (int*)alloc((size_t)NEDGES * 4);
    int*   part    = (int*)alloc((size_t)NSB * 4);
    unsigned* csr4 = (unsigned*)alloc((size_t)NEDGES * 4);
    int*   blockHist = (int*)alloc((size_t)NBINS * NSB * 4);
    int*   perm    = (int*)alloc((size_t)NNODES * 4);
    float* colA    = (float*)alloc((size_t)NLAYERS * DIM * 4);
    float* colB    = (float*)alloc((size_t)NLAYERS * DIM * 4);
    unsigned short* W1T = (unsigned short*)alloc((size_t)NLAYERS * DIM * DIM * 2);
    unsigned short* W2T = (unsigned short*)alloc((size_t)NLAYERS * DIM * DIM * 2);
    float* POOL    = (float*)alloc((size_t)NGRAPH * DIM * 4);

    // deg: 12500 int4; POOL: 8192 int4
    zero_bufs<<<(12500 + 255) / 256, 256, 0, stream>>>((int4*)deg, 12500, (int4*)POOL, 8192);

    count_deg<<<(NEDGES + 255) / 256, 256, 0, stream>>>(dstp, deg, rank, NEDGES);
    partial_sum<<<NSB, SCAN_BLK, 0, stream>>>(deg, part, NNODES);
    scan_partials<<<1, 256, 0, stream>>>(part, NSB);
    emit_offsets<<<NSB, SCAN_BLK, 0, stream>>>(deg, part, off, NNODES);
    place_csr<<<(NEDGES + 255) / 256, 256, 0, stream>>>(srcp, dstp, emask, off, rank, csr4, NEDGES);
    hist_block<<<NSB, 256, 0, stream>>>(deg, snmask, blockHist, NNODES);
    scan_matrix<<<1, 1024, 0, stream>>>(blockHist, NBINS * NSB);
    place_block<<<NSB, 256, 0, stream>>>(deg, snmask, blockHist, perm, NNODES);
    prep_bn<<<(NLAYERS * DIM + 255) / 256, 256, 0, stream>>>(gamma, beta, mean, var, bs1, colA, colB, NLAYERS * DIM);
    prep_wt<<<(NLAYERS * DIM * DIM + 255) / 256, 256, 0, stream>>>(Ws1, Ws2, W1T, W2T, NLAYERS * DIM * DIM);
    conv_x<<<(NNODES * DIM / 4 + 255) / 256, 256, 0, stream>>>(x, XB, NNODES * DIM / 4);

    const int nWaves = (NNODES + 3) / 4;
    const int gatherBlocks = (nWaves * 64 + 255) / 256;
    gather0<<<gatherBlocks, 256, 0, stream>>>(XB, off, deg, csr4, snmask, perm, X, NNODES);

    // ping-pong: X -> H -> X -> H
    const unsigned short* bufs[4] = {X, H, X, H};
    const int layerBlocks = (NNODES + 63) / 64;
    for (int l = 0; l < NLAYERS; ++l) {
        gin_layer<<<layerBlocks, 512, 0, stream>>>((const unsigned short*)bufs[l],
                                                   (unsigned short*)bufs[l + 1],
                                                   off, deg, csr4, perm,
                                                   W1T + (size_t)l * DIM * DIM,
                                                   W2T + (size_t)l * DIM * DIM,
                                                   colA + (size_t)l * DIM,
                                                   colB + (size_t)l * DIM,
                                                   bs2 + (size_t)l * DIM, NNODES);
    }

    pool_kernel<<<(NNODES + 127) / 128, 128, 0, stream>>>(H, batch, POOL, NNODES);
    final_mlp<<<NGRAPH, 128, 0, stream>>>(POOL, Wf1, bf1, Wf2, bf2, out);
}

// Round 14
// 278.920 us; speedup vs baseline: 1.0886x; 1.0319x over previous
//
#include <hip/hip_runtime.h>
#include <hip/hip_bf16.h>
#include <hip/hip_fp16.h>

#define NNODES 50000
#define NEDGES 600000
#define DIM    128
#define NLAYERS 3
#define NCLS   10
#define NGRAPH 256
#define BN_EPS 1e-5f

#define SCAN_BLK 256
#define NSB ((NNODES + SCAN_BLK - 1) / SCAN_BLK)   // 196 blocks
#define NBINS 128   // key = (snmask<<6) | min(deg,63)

typedef __attribute__((ext_vector_type(8))) short bf16x8;   // 8 bf16 = 4 VGPR
typedef __attribute__((ext_vector_type(4))) float f32x4;

static __device__ __forceinline__ unsigned short f2b(float f) {
    union { __hip_bfloat16 h; unsigned short u; } c;
    c.h = __float2bfloat16(f);
    return c.u;
}
static __device__ __forceinline__ float b2f(short s) {
    return __uint_as_float(((unsigned)(unsigned short)s) << 16);
}
static __device__ __forceinline__ unsigned pack2(float a, float b) {
    return (unsigned)f2b(a) | ((unsigned)f2b(b) << 16);
}

// ---------------- workspace zeroing ----------------
__global__ __launch_bounds__(256) void zero_bufs(int4* __restrict__ a, int na,
                                                 int4* __restrict__ b, int nb) {
    int i = blockIdx.x * 256 + threadIdx.x;
    int4 z = make_int4(0, 0, 0, 0);
    if (i < na) a[i] = z;
    if (i < nb) b[i] = z;
}

// ---------------- CSR build ----------------
__global__ void count_deg(const int* __restrict__ dst, int* __restrict__ deg,
                          int* __restrict__ rank, int E) {
    int e = blockIdx.x * blockDim.x + threadIdx.x;
    if (e < E) rank[e] = atomicAdd(&deg[dst[e]], 1);
}

__global__ __launch_bounds__(SCAN_BLK) void partial_sum(const int* __restrict__ deg,
                                                        int* __restrict__ part, int n) {
    int t = threadIdx.x;
    int i = blockIdx.x * SCAN_BLK + t;
    int v = (i < n) ? deg[i] : 0;
#pragma unroll
    for (int o = 32; o > 0; o >>= 1) v += __shfl_down(v, o, 64);
    __shared__ int s[SCAN_BLK / 64];
    if ((t & 63) == 0) s[t >> 6] = v;
    __syncthreads();
    if (t == 0) {
        int sum = 0;
#pragma unroll
        for (int w = 0; w < SCAN_BLK / 64; ++w) sum += s[w];
        part[blockIdx.x] = sum;
    }
}

__global__ __launch_bounds__(256) void scan_partials(int* __restrict__ part, int nb) {
    __shared__ int s[256];
    int t = threadIdx.x;
    int v = (t < nb) ? part[t] : 0;
    s[t] = v;
    __syncthreads();
    for (int o = 1; o < 256; o <<= 1) {
        int u = (t >= o) ? s[t - o] : 0;
        __syncthreads();
        s[t] += u;
        __syncthreads();
    }
    if (t < nb) part[t] = (t == 0) ? 0 : s[t - 1];
}

__global__ __launch_bounds__(SCAN_BLK) void emit_offsets(const int* __restrict__ deg,
                                                         const int* __restrict__ part,
                                                         int* __restrict__ off, int n) {
    __shared__ int s[SCAN_BLK];
    int t = threadIdx.x;
    int i = blockIdx.x * SCAN_BLK + t;
    int v = (i < n) ? deg[i] : 0;
    s[t] = v;
    __syncthreads();
    for (int o = 1; o < SCAN_BLK; o <<= 1) {
        int u = (t >= o) ? s[t - o] : 0;
        __syncthreads();
        s[t] += u;
        __syncthreads();
    }
    if (i < n) off[i] = part[blockIdx.x] + s[t] - v;
}

// pure scatter, no atomics: 4B per edge (low16 src, high16 f16 weight)
__global__ void place_csr(const int* __restrict__ src, const int* __restrict__ dst,
                          const float* __restrict__ emask,
                          const int* __restrict__ off, const int* __restrict__ rank,
                          unsigned* __restrict__ csr4, int E) {
    int e = blockIdx.x * blockDim.x + threadIdx.x;
    if (e < E) {
        int d = dst[e];
        unsigned wbits = (unsigned)__half_as_ushort(__float2half(emask[e]));
        csr4[off[d] + rank[e]] = (unsigned)src[e] | (wbits << 16);
    }
}

// ---------------- (snmask, degree)-keyed permutation: contention-free counting sort ----------------

static __device__ __forceinline__ int sort_key(int sn, int dg) {
    int b = dg > 63 ? 63 : dg;
    return (sn ? 64 : 0) | b;
}

__global__ __launch_bounds__(256) void hist_block(const int* __restrict__ deg,
                                                  const int* __restrict__ snmask,
                                                  int* __restrict__ blockHist, int n) {
    __shared__ int h[NBINS];
    int t = threadIdx.x;
    if (t < NBINS) h[t] = 0;
    __syncthreads();
    int i = blockIdx.x * 256 + t;
    if (i < n) atomicAdd(&h[sort_key(snmask[i], deg[i])], 1);   // LDS atomic
    __syncthreads();
    if (t < NBINS) blockHist[t * NSB + blockIdx.x] = h[t];      // bin-major
}

__global__ __launch_bounds__(1024) void scan_matrix(int* __restrict__ m, int total) {
    __shared__ int s[1024];
    int t = threadIdx.x;
    const int CH = (total + 1023) / 1024;   // 25
    int lo = t * CH;
    int hi = lo + CH; if (hi > total) hi = total;
    int sum = 0;
    for (int i = lo; i < hi; ++i) sum += m[i];
    s[t] = sum;
    __syncthreads();
    for (int o = 1; o < 1024; o <<= 1) {
        int v = (t >= o) ? s[t - o] : 0;
        __syncthreads();
        s[t] += v;
        __syncthreads();
    }
    int run = (t == 0) ? 0 : s[t - 1];
    for (int i = lo; i < hi; ++i) {
        int v = m[i]; m[i] = run; run += v;
    }
}

__global__ __launch_bounds__(256) void place_block(const int* __restrict__ deg,
                                                   const int* __restrict__ snmask,
                                                   const int* __restrict__ blockHist,
                                                   int* __restrict__ perm, int n) {
    __shared__ int h[NBINS];
    int t = threadIdx.x;
    if (t < NBINS) h[t] = 0;
    __syncthreads();
    int i = blockIdx.x * 256 + t;
    if (i < n) {
        int b = sort_key(snmask[i], deg[i]);
        int r = atomicAdd(&h[b], 1);   // LDS rank within (block, bin)
        perm[blockHist[b * NSB + blockIdx.x] + r] = i;
    }
}

// ---------------- prep: BN fold, W transpose->bf16, x->bf16 ----------------

__global__ void prep_bn(const float* __restrict__ gamma, const float* __restrict__ beta,
                        const float* __restrict__ mean, const float* __restrict__ var,
                        const float* __restrict__ b1,
                        float* __restrict__ colA, float* __restrict__ colB, int n) {
    int i = blockIdx.x * blockDim.x + threadIdx.x;
    if (i < n) {
        float A = gamma[i] * rsqrtf(var[i] + BN_EPS);
        colA[i] = A;
        colB[i] = beta[i] - mean[i] * A + b1[i] * A;
    }
}

// W[l][k][n] f32  ->  WT[l][n][k] bf16
__global__ void prep_wt(const float* __restrict__ W1, const float* __restrict__ W2,
                        unsigned short* __restrict__ W1T, unsigned short* __restrict__ W2T, int total) {
    int i = blockIdx.x * blockDim.x + threadIdx.x;
    if (i < total) {
        int l  = i / (DIM * DIM);
        int r  = i - l * DIM * DIM;
        int nn = r / DIM;
        int kk = r - nn * DIM;
        int sidx = l * DIM * DIM + kk * DIM + nn;
        W1T[i] = f2b(W1[sidx]);
        W2T[i] = f2b(W2[sidx]);
    }
}

__global__ void conv_x(const float* __restrict__ x, unsigned short* __restrict__ xb, int n4) {
    int i = blockIdx.x * blockDim.x + threadIdx.x;
    if (i < n4) {
        float4 v = ((const float4*)x)[i];
        unsigned lo = pack2(v.x, v.y);
        unsigned hi = pack2(v.z, v.w);
        ((uint2*)xb)[i] = make_uint2(lo, hi);
    }
}

// ---------------- gather0: weighted SimpleConv for SUPERNODES ONLY; copy otherwise ----------------
// REVERSED index order (LPT): heavy sn nodes (top of perm) dispatch first; light copy
// nodes fill the scheduling tail.

__global__ __launch_bounds__(256) void gather0(const unsigned short* __restrict__ xb,
                                               const int* __restrict__ off, const int* __restrict__ deg,
                                               const unsigned* __restrict__ csr4,
                                               const int* __restrict__ snmask,
                                               const int* __restrict__ perm,
                                               unsigned short* __restrict__ X, int n) {
    int wave = (blockIdx.x * blockDim.x + threadIdx.x) >> 6;
    int lane = threadIdx.x & 63;
    int q    = lane >> 4;
    int l16  = lane & 15;
    int fidx = wave * 4 + q;
    bool valid = fidx < n;
    int idx  = n - 1 - (valid ? fidx : 0);   // reversed: heaviest first
    int node = perm[idx];
    int base = off[node];
    bool sn  = valid && snmask[node];
    int dg   = sn ? deg[node] : 0;   // non-supernode: skip gather entirely

    float acc[8];
#pragma unroll
    for (int i = 0; i < 8; ++i) acc[i] = 0.f;

    int j = 0;
    for (; j + 8 <= dg; j += 8) {
        unsigned cc[8];
#pragma unroll
        for (int u = 0; u < 8; ++u) cc[u] = csr4[base + j + u];
        bf16x8 vv[8];
#pragma unroll
        for (int u = 0; u < 8; ++u)
            vv[u] = *(const bf16x8*)&xb[(long)(cc[u] & 0xffffu) * DIM + l16 * 8];
#pragma unroll
        for (int u = 0; u < 8; ++u) {
            float w = __half2float(__ushort_as_half((unsigned short)(cc[u] >> 16)));
#pragma unroll
            for (int i = 0; i < 8; ++i) acc[i] = fmaf(w, b2f(vv[u][i]), acc[i]);
        }
    }
    for (; j + 4 <= dg; j += 4) {
        unsigned cc[4];
#pragma unroll
        for (int u = 0; u < 4; ++u) cc[u] = csr4[base + j + u];
        bf16x8 vv[4];
#pragma unroll
        for (int u = 0; u < 4; ++u)
            vv[u] = *(const bf16x8*)&xb[(long)(cc[u] & 0xffffu) * DIM + l16 * 8];
#pragma unroll
        for (int u = 0; u < 4; ++u) {
            float w = __half2float(__ushort_as_half((unsigned short)(cc[u] >> 16)));
#pragma unroll
            for (int i = 0; i < 8; ++i) acc[i] = fmaf(w, b2f(vv[u][i]), acc[i]);
        }
    }
    for (; j < dg; ++j) {
        unsigned c = csr4[base + j];
        float w = __half2float(__ushort_as_half((unsigned short)(c >> 16)));
        bf16x8 v = *(const bf16x8*)&xb[(long)(c & 0xffffu) * DIM + l16 * 8];
#pragma unroll
        for (int i = 0; i < 8; ++i) acc[i] = fmaf(w, b2f(v[i]), acc[i]);
    }

    if (valid) {
        bf16x8 res;
        if (sn) {
#pragma unroll
            for (int i = 0; i < 8; ++i) res[i] = (short)f2b(acc[i]);
        } else {
            res = *(const bf16x8*)&xb[(long)node * DIM + l16 * 8];
        }
        *(bf16x8*)&X[(long)node * DIM + l16 * 8] = res;
    }
}

// ---------------- fused GIN layer: gather(LDS) -> GEMM1 -> GEMM2 ----------------
// 512 threads = 8 waves, 64 rows/block. CONTIGUOUS-DESCENDING block mapping:
// block b covers perm rows (nb-1-b)*64.. -> sorted-uniform degree within each block
// (no intra-block straggler at the barrier) AND heavy blocks dispatch first (LPT,
// light tail). Round-11's dealt mapping stratified degrees -> every block waited on
// a deg~22+ group; round-10's ascending order tail-clustered the heavy blocks.
#define HPITCH 136   // bf16 elems; 272B rows: 16B-aligned, 2-way LDS aliasing only

__global__ __launch_bounds__(512) void gin_layer(const unsigned short* __restrict__ Xin,
                                                 unsigned short* __restrict__ Xout,
                                                 const int* __restrict__ off, const int* __restrict__ deg,
                                                 const unsigned* __restrict__ csr4,
                                                 const int* __restrict__ perm,
                                                 const unsigned short* __restrict__ W1T,
                                                 const unsigned short* __restrict__ W2T,
                                                 const float* __restrict__ colA, const float* __restrict__ colB,
                                                 const float* __restrict__ b2, int n) {
    __shared__ unsigned short h_in[64 * HPITCH];
    __shared__ unsigned short h_t[64 * HPITCH];
    int t    = threadIdx.x;
    int wid  = t >> 6;
    int lane = t & 63;
    int q    = lane >> 4;
    int l16  = lane & 15;
    int lm   = lane & 15;
    int lk   = (lane >> 4) * 8;
    int wr   = wid >> 2;          // 0..1
    int wc   = wid & 3;           // 0..3
    int c0   = wc * 32;
    int nb   = gridDim.x;
    int row0 = (nb - 1 - (int)blockIdx.x) * 64;   // descending-contiguous

    // ---- W1 B-fragments first: weight fetch overlaps gather latency ----
    bf16x8 b1[2][4];
#pragma unroll
    for (int cs = 0; cs < 2; ++cs)
#pragma unroll
        for (int ks = 0; ks < 4; ++ks) {
            int col = c0 + cs * 16 + lm;
            b1[cs][ks] = *(const bf16x8*)&W1T[col * DIM + ks * 32 + lk];
        }

    // ---- gather phase: GIN eps=0 agg into h_in (sorted-uniform quarter-waves) ----
#pragma unroll
    for (int rnd = 0; rnd < 2; ++rnd) {
        int lrow = wid * 8 + rnd * 4 + q;
        int idx  = row0 + lrow;
        bool valid = idx < n;
        int node = perm[valid ? idx : (n - 1)];
        int base = off[node];
        int dg   = valid ? deg[node] : 0;

        float acc[8];
        {
            bf16x8 self = *(const bf16x8*)&Xin[(long)node * DIM + l16 * 8];
#pragma unroll
            for (int i = 0; i < 8; ++i) acc[i] = b2f(self[i]);
        }
        int j = 0;
        for (; j + 8 <= dg; j += 8) {
            unsigned ee[8];
#pragma unroll
            for (int u = 0; u < 8; ++u) ee[u] = csr4[base + j + u];
            bf16x8 vv[8];
#pragma unroll
            for (int u = 0; u < 8; ++u)
                vv[u] = *(const bf16x8*)&Xin[(long)(ee[u] & 0xffffu) * DIM + l16 * 8];
#pragma unroll
            for (int u = 0; u < 8; ++u)
#pragma unroll
                for (int i = 0; i < 8; ++i) acc[i] += b2f(vv[u][i]);
        }
        for (; j + 4 <= dg; j += 4) {
            unsigned ee[4];
#pragma unroll
            for (int u = 0; u < 4; ++u) ee[u] = csr4[base + j + u];
            bf16x8 vv[4];
#pragma unroll
            for (int u = 0; u < 4; ++u)
                vv[u] = *(const bf16x8*)&Xin[(long)(ee[u] & 0xffffu) * DIM + l16 * 8];
#pragma unroll
            for (int u = 0; u < 4; ++u)
#pragma unroll
                for (int i = 0; i < 8; ++i) acc[i] += b2f(vv[u][i]);
        }
        for (; j < dg; ++j) {
            unsigned e = csr4[base + j];
            bf16x8 v = *(const bf16x8*)&Xin[(long)(e & 0xffffu) * DIM + l16 * 8];
#pragma unroll
            for (int i = 0; i < 8; ++i) acc[i] += b2f(v[i]);
        }
        bf16x8 r;
#pragma unroll
        for (int i = 0; i < 8; ++i) r[i] = valid ? (short)f2b(acc[i]) : (short)0;
        *(bf16x8*)&h_in[lrow * HPITCH + l16 * 8] = r;
    }
    __syncthreads();

    // ---- GEMM1 ----
    bf16x8 a[2][4];
#pragma unroll
    for (int rs = 0; rs < 2; ++rs)
#pragma unroll
        for (int ks = 0; ks < 4; ++ks)
            a[rs][ks] = *(const bf16x8*)&h_in[(wr * 32 + rs * 16 + lm) * HPITCH + ks * 32 + lk];

    f32x4 acc[2][2];
    f32x4 z = {0.f, 0.f, 0.f, 0.f};
#pragma unroll
    for (int rs = 0; rs < 2; ++rs)
#pragma unroll
        for (int cs = 0; cs < 2; ++cs) acc[rs][cs] = z;

#pragma unroll
    for (int ks = 0; ks < 4; ++ks)
#pragma unroll
        for (int rs = 0; rs < 2; ++rs)
#pragma unroll
            for (int cs = 0; cs < 2; ++cs)
                acc[rs][cs] = __builtin_amdgcn_mfma_f32_16x16x32_bf16(a[rs][ks], b1[cs][ks], acc[rs][cs], 0, 0, 0);

    // ---- epilogue 1: affine(BN)+ReLU -> h_t ----
#pragma unroll
    for (int rs = 0; rs < 2; ++rs)
#pragma unroll
        for (int cs = 0; cs < 2; ++cs) {
            int colv = c0 + cs * 16 + lm;
            float cA = colA[colv], cB = colB[colv];
            int rbase = wr * 32 + rs * 16 + (lane >> 4) * 4;
            f32x4 av = acc[rs][cs];
#pragma unroll
            for (int v = 0; v < 4; ++v) {
                float h = fmaxf(fmaf(av[v], cA, cB), 0.f);
                h_t[(rbase + v) * HPITCH + colv] = f2b(h);
            }
        }
    __syncthreads();

    // ---- GEMM2 ----
    bf16x8 a2[2][4];
#pragma unroll
    for (int rs = 0; rs < 2; ++rs)
#pragma unroll
        for (int ks = 0; ks < 4; ++ks)
            a2[rs][ks] = *(const bf16x8*)&h_t[(wr * 32 + rs * 16 + lm) * HPITCH + ks * 32 + lk];

    bf16x8 b2f_[2][4];
#pragma unroll
    for (int cs = 0; cs < 2; ++cs)
#pragma unroll
        for (int ks = 0; ks < 4; ++ks) {
            int col = c0 + cs * 16 + lm;
            b2f_[cs][ks] = *(const bf16x8*)&W2T[col * DIM + ks * 32 + lk];
        }

#pragma unroll
    for (int rs = 0; rs < 2; ++rs)
#pragma unroll
        for (int cs = 0; cs < 2; ++cs) acc[rs][cs] = z;

#pragma unroll
    for (int ks = 0; ks < 4; ++ks)
#pragma unroll
        for (int rs = 0; rs < 2; ++rs)
#pragma unroll
            for (int cs = 0; cs < 2; ++cs)
                acc[rs][cs] = __builtin_amdgcn_mfma_f32_16x16x32_bf16(a2[rs][ks], b2f_[cs][ks], acc[rs][cs], 0, 0, 0);

    __syncthreads();

    // ---- epilogue 2: +bias, ReLU -> h_t ----
#pragma unroll
    for (int rs = 0; rs < 2; ++rs)
#pragma unroll
        for (int cs = 0; cs < 2; ++cs) {
            int colv = c0 + cs * 16 + lm;
            float bb = b2[colv];
            int rbase = wr * 32 + rs * 16 + (lane >> 4) * 4;
            f32x4 av = acc[rs][cs];
#pragma unroll
            for (int v = 0; v < 4; ++v) {
                float h = fmaxf(av[v] + bb, 0.f);
                h_t[(rbase + v) * HPITCH + colv] = f2b(h);
            }
        }
    __syncthreads();

    // ---- copy-out: row -> descending-contiguous idx -> Xout[perm[idx]] ----
    {
        int row = t >> 3;
        int ch  = (t & 7) * 16;
        int idx = row0 + row;
        if (idx < n) {
            int node = perm[idx];
            *(bf16x8*)&Xout[(long)node * DIM + ch]     = *(const bf16x8*)&h_t[row * HPITCH + ch];
            *(bf16x8*)&Xout[(long)node * DIM + ch + 8] = *(const bf16x8*)&h_t[row * HPITCH + ch + 8];
        }
    }
}

// ---------------- pool (batch sorted -> run-accumulate) ----------------

__global__ __launch_bounds__(128) void pool_kernel(const unsigned short* __restrict__ X,
                                                   const int* __restrict__ batch,
                                                   float* __restrict__ POOL, int n) {
    int c  = threadIdx.x;
    int n0 = blockIdx.x * 128;
    if (n0 >= n) return;
    int n1 = n0 + 128; if (n1 > n) n1 = n;
    int gcur = batch[n0];
    float acc = 0.f;
    for (int i = n0; i < n1; ++i) {
        int g = batch[i];
        if (g != gcur) {
            atomicAdd(&POOL[(long)gcur * DIM + c], acc);
            acc = 0.f; gcur = g;
        }
        acc += __uint_as_float(((unsigned)X[(long)i * DIM + c]) << 16);
    }
    atomicAdd(&POOL[(long)gcur * DIM + c], acc);
}

// ---------------- final head ----------------

__global__ __launch_bounds__(128) void final_mlp(const float* __restrict__ POOL,
                                                 const float* __restrict__ Wf1, const float* __restrict__ bf1,
                                                 const float* __restrict__ Wf2, const float* __restrict__ bf2,
                                                 float* __restrict__ out) {
    int g = blockIdx.x;
    int t = threadIdx.x;
    __shared__ float p[128];
    __shared__ float h[128];
    p[t] = POOL[(long)g * DIM + t];
    __syncthreads();
    float acc = bf1[t];
#pragma unroll 8
    for (int k = 0; k < DIM; ++k) acc = fmaf(p[k], Wf1[k * DIM + t], acc);
    h[t] = fmaxf(acc, 0.f);
    __syncthreads();
    if (t < NCLS) {
        float acc2 = bf2[t];
#pragma unroll 8
        for (int k = 0; k < DIM; ++k) acc2 = fmaf(h[k], Wf2[k * NCLS + t], acc2);
        out[(long)g * NCLS + t] = acc2;
    }
}

// ---------------- launch ----------------

extern "C" void kernel_launch(void* const* d_in, const int* in_sizes, int n_in,
                              void* d_out, int out_size, void* d_ws, size_t ws_size,
                              hipStream_t stream) {
    const float* x      = (const float*)d_in[0];
    const int*   ei     = (const int*)d_in[1];
    const int*   snmask = (const int*)d_in[2];
    const float* emask  = (const float*)d_in[3];
    const int*   batch  = (const int*)d_in[4];
    const float* Ws1    = (const float*)d_in[5];
    const float* bs1    = (const float*)d_in[6];
    const float* gamma  = (const float*)d_in[7];
    const float* beta   = (const float*)d_in[8];
    const float* mean   = (const float*)d_in[9];
    const float* var    = (const float*)d_in[10];
    const float* Ws2    = (const float*)d_in[11];
    const float* bs2    = (const float*)d_in[12];
    const float* Wf1    = (const float*)d_in[13];
    const float* bf1    = (const float*)d_in[14];
    const float* Wf2    = (const float*)d_in[15];
    const float* bf2    = (const float*)d_in[16];
    float* out = (float*)d_out;

    const int* srcp = ei;
    const int* dstp = ei + NEDGES;

    char* ws = (char*)d_ws;
    size_t o = 0;
    auto alloc = [&](size_t bytes) -> void* {
        void* p = ws + o;
        o = (o + bytes + 255) & ~(size_t)255;
        return p;
    };
    unsigned short* XB  = (unsigned short*)alloc((size_t)NNODES * DIM * 2);
    unsigned short* X   = (unsigned short*)alloc((size_t)NNODES * DIM * 2);
    unsigned short* H   = (unsigned short*)alloc((size_t)NNODES * DIM * 2);
    int*   deg     = (int*)alloc((size_t)NNODES * 4);
    int*   off     = (int*)alloc((size_t)NNODES * 4);
    int*   rank    = (int*)alloc((size_t)NEDGES * 4);
    int*   part    = (int*)alloc((size_t)NSB * 4);
    unsigned* csr4 = (unsigned*)alloc((size_t)NEDGES * 4);
    int*   blockHist = (int*)alloc((size_t)NBINS * NSB * 4);
    int*   perm    = (int*)alloc((size_t)NNODES * 4);
    float* colA    = (float*)alloc((size_t)NLAYERS * DIM * 4);
    float* colB    = (float*)alloc((size_t)NLAYERS * DIM * 4);
    unsigned short* W1T = (unsigned short*)alloc((size_t)NLAYERS * DIM * DIM * 2);
    unsigned short* W2T = (unsigned short*)alloc((size_t)NLAYERS * DIM * DIM * 2);
    float* POOL    = (float*)alloc((size_t)NGRAPH * DIM * 4);

    // deg: 12500 int4; POOL: 8192 int4
    zero_bufs<<<(12500 + 255) / 256, 256, 0, stream>>>((int4*)deg, 12500, (int4*)POOL, 8192);

    count_deg<<<(NEDGES + 255) / 256, 256, 0, stream>>>(dstp, deg, rank, NEDGES);
    partial_sum<<<NSB, SCAN_BLK, 0, stream>>>(deg, part, NNODES);
    scan_partials<<<1, 256, 0, stream>>>(part, NSB);
    emit_offsets<<<NSB, SCAN_BLK, 0, stream>>>(deg, part, off, NNODES);
    place_csr<<<(NEDGES + 255) / 256, 256, 0, stream>>>(srcp, dstp, emask, off, rank, csr4, NEDGES);
    hist_block<<<NSB, 256, 0, stream>>>(deg, snmask, blockHist, NNODES);
    scan_matrix<<<1, 1024, 0, stream>>>(blockHist, NBINS * NSB);
    place_block<<<NSB, 256, 0, stream>>>(deg, snmask, blockHist, perm, NNODES);
    prep_bn<<<(NLAYERS * DIM + 255) / 256, 256, 0, stream>>>(gamma, beta, mean, var, bs1, colA, colB, NLAYERS * DIM);
    prep_wt<<<(NLAYERS * DIM * DIM + 255) / 256, 256, 0, stream>>>(Ws1, Ws2, W1T, W2T, NLAYERS * DIM * DIM);
    conv_x<<<(NNODES * DIM / 4 + 255) / 256, 256, 0, stream>>>(x, XB, NNODES * DIM / 4);

    const int nWaves = (NNODES + 3) / 4;
    const int gatherBlocks = (nWaves * 64 + 255) / 256;
    gather0<<<gatherBlocks, 256, 0, stream>>>(XB, off, deg, csr4, snmask, perm, X, NNODES);

    // ping-pong: X -> H -> X -> H
    const unsigned short* bufs[4] = {X, H, X, H};
    const int layerBlocks = (NNODES + 63) / 64;
    for (int l = 0; l < NLAYERS; ++l) {
        gin_layer<<<layerBlocks, 512, 0, stream>>>((const unsigned short*)bufs[l],
                                                   (unsigned short*)bufs[l + 1],
                                                   off, deg, csr4, perm,
                                                   W1T + (size_t)l * DIM * DIM,
                                                   W2T + (size_t)l * DIM * DIM,
                                                   colA + (size_t)l * DIM,
                                                   colB + (size_t)l * DIM,
                                                   bs2 + (size_t)l * DIM, NNODES);
    }

    pool_kernel<<<(NNODES + 127) / 128, 128, 0, stream>>>(H, batch, POOL, NNODES);
    final_mlp<<<NGRAPH, 128, 0, stream>>>(POOL, Wf1, bf1, Wf2, bf2, out);
}

// Round 15
// 245.159 us; speedup vs baseline: 1.2386x; 1.1377x over previous
//
#include <hip/hip_runtime.h>
#include <hip/hip_bf16.h>
#include <hip/hip_fp16.h>

#define NNODES 50000
#define NEDGES 600000
#define DIM    128
#define NLAYERS 3
#define NCLS   10
#define NGRAPH 256
#define BN_EPS 1e-5f

#define SCAN_BLK 256
#define NSB ((NNODES + SCAN_BLK - 1) / SCAN_BLK)   // 196 blocks
#define NBINS 128   // key = (snmask<<6) | min(deg,63)

typedef __attribute__((ext_vector_type(8))) short bf16x8;   // 8 bf16 = 4 VGPR
typedef __attribute__((ext_vector_type(4))) float f32x4;

static __device__ __forceinline__ unsigned short f2b(float f) {
    union { __hip_bfloat16 h; unsigned short u; } c;
    c.h = __float2bfloat16(f);
    return c.u;
}
static __device__ __forceinline__ float b2f(short s) {
    return __uint_as_float(((unsigned)(unsigned short)s) << 16);
}
static __device__ __forceinline__ unsigned pack2(float a, float b) {
    return (unsigned)f2b(a) | ((unsigned)f2b(b) << 16);
}

// ---------------- workspace zeroing ----------------
__global__ __launch_bounds__(256) void zero_bufs(int4* __restrict__ a, int na,
                                                 int4* __restrict__ b, int nb) {
    int i = blockIdx.x * 256 + threadIdx.x;
    int4 z = make_int4(0, 0, 0, 0);
    if (i < na) a[i] = z;
    if (i < nb) b[i] = z;
}

// ---------------- CSR build ----------------
__global__ void count_deg(const int* __restrict__ dst, int* __restrict__ deg,
                          int* __restrict__ rank, int E) {
    int e = blockIdx.x * blockDim.x + threadIdx.x;
    if (e < E) rank[e] = atomicAdd(&deg[dst[e]], 1);
}

__global__ __launch_bounds__(SCAN_BLK) void partial_sum(const int* __restrict__ deg,
                                                        int* __restrict__ part, int n) {
    int t = threadIdx.x;
    int i = blockIdx.x * SCAN_BLK + t;
    int v = (i < n) ? deg[i] : 0;
#pragma unroll
    for (int o = 32; o > 0; o >>= 1) v += __shfl_down(v, o, 64);
    __shared__ int s[SCAN_BLK / 64];
    if ((t & 63) == 0) s[t >> 6] = v;
    __syncthreads();
    if (t == 0) {
        int sum = 0;
#pragma unroll
        for (int w = 0; w < SCAN_BLK / 64; ++w) sum += s[w];
        part[blockIdx.x] = sum;
    }
}

__global__ __launch_bounds__(256) void scan_partials(int* __restrict__ part, int nb) {
    __shared__ int s[256];
    int t = threadIdx.x;
    int v = (t < nb) ? part[t] : 0;
    s[t] = v;
    __syncthreads();
    for (int o = 1; o < 256; o <<= 1) {
        int u = (t >= o) ? s[t - o] : 0;
        __syncthreads();
        s[t] += u;
        __syncthreads();
    }
    if (t < nb) part[t] = (t == 0) ? 0 : s[t - 1];
}

__global__ __launch_bounds__(SCAN_BLK) void emit_offsets(const int* __restrict__ deg,
                                                         const int* __restrict__ part,
                                                         int* __restrict__ off, int n) {
    __shared__ int s[SCAN_BLK];
    int t = threadIdx.x;
    int i = blockIdx.x * SCAN_BLK + t;
    int v = (i < n) ? deg[i] : 0;
    s[t] = v;
    __syncthreads();
    for (int o = 1; o < SCAN_BLK; o <<= 1) {
        int u = (t >= o) ? s[t - o] : 0;
        __syncthreads();
        s[t] += u;
        __syncthreads();
    }
    if (i < n) off[i] = part[blockIdx.x] + s[t] - v;
}

// pure scatter, no atomics: 4B per edge (low16 src, high16 f16 weight)
__global__ void place_csr(const int* __restrict__ src, const int* __restrict__ dst,
                          const float* __restrict__ emask,
                          const int* __restrict__ off, const int* __restrict__ rank,
                          unsigned* __restrict__ csr4, int E) {
    int e = blockIdx.x * blockDim.x + threadIdx.x;
    if (e < E) {
        int d = dst[e];
        unsigned wbits = (unsigned)__half_as_ushort(__float2half(emask[e]));
        csr4[off[d] + rank[e]] = (unsigned)src[e] | (wbits << 16);
    }
}

// ---------------- (snmask, degree)-keyed permutation: contention-free counting sort ----------------

static __device__ __forceinline__ int sort_key(int sn, int dg) {
    int b = dg > 63 ? 63 : dg;
    return (sn ? 64 : 0) | b;
}

__global__ __launch_bounds__(256) void hist_block(const int* __restrict__ deg,
                                                  const int* __restrict__ snmask,
                                                  int* __restrict__ blockHist, int n) {
    __shared__ int h[NBINS];
    int t = threadIdx.x;
    if (t < NBINS) h[t] = 0;
    __syncthreads();
    int i = blockIdx.x * 256 + t;
    if (i < n) atomicAdd(&h[sort_key(snmask[i], deg[i])], 1);   // LDS atomic
    __syncthreads();
    if (t < NBINS) blockHist[t * NSB + blockIdx.x] = h[t];      // bin-major
}

__global__ __launch_bounds__(1024) void scan_matrix(int* __restrict__ m, int total) {
    __shared__ int s[1024];
    int t = threadIdx.x;
    const int CH = (total + 1023) / 1024;   // 25
    int lo = t * CH;
    int hi = lo + CH; if (hi > total) hi = total;
    int sum = 0;
    for (int i = lo; i < hi; ++i) sum += m[i];
    s[t] = sum;
    __syncthreads();
    for (int o = 1; o < 1024; o <<= 1) {
        int v = (t >= o) ? s[t - o] : 0;
        __syncthreads();
        s[t] += v;
        __syncthreads();
    }
    int run = (t == 0) ? 0 : s[t - 1];
    for (int i = lo; i < hi; ++i) {
        int v = m[i]; m[i] = run; run += v;
    }
}

__global__ __launch_bounds__(256) void place_block(const int* __restrict__ deg,
                                                   const int* __restrict__ snmask,
                                                   const int* __restrict__ blockHist,
                                                   int* __restrict__ perm, int n) {
    __shared__ int h[NBINS];
    int t = threadIdx.x;
    if (t < NBINS) h[t] = 0;
    __syncthreads();
    int i = blockIdx.x * 256 + t;
    if (i < n) {
        int b = sort_key(snmask[i], deg[i]);
        int r = atomicAdd(&h[b], 1);   // LDS rank within (block, bin)
        perm[blockHist[b * NSB + blockIdx.x] + r] = i;
    }
}

// ---------------- prep: BN fold, W transpose->bf16, x->bf16 ----------------

__global__ void prep_bn(const float* __restrict__ gamma, const float* __restrict__ beta,
                        const float* __restrict__ mean, const float* __restrict__ var,
                        const float* __restrict__ b1,
                        float* __restrict__ colA, float* __restrict__ colB, int n) {
    int i = blockIdx.x * blockDim.x + threadIdx.x;
    if (i < n) {
        float A = gamma[i] * rsqrtf(var[i] + BN_EPS);
        colA[i] = A;
        colB[i] = beta[i] - mean[i] * A + b1[i] * A;
    }
}

// W[l][k][n] f32  ->  WT[l][n][k] bf16
__global__ void prep_wt(const float* __restrict__ W1, const float* __restrict__ W2,
                        unsigned short* __restrict__ W1T, unsigned short* __restrict__ W2T, int total) {
    int i = blockIdx.x * blockDim.x + threadIdx.x;
    if (i < total) {
        int l  = i / (DIM * DIM);
        int r  = i - l * DIM * DIM;
        int nn = r / DIM;
        int kk = r - nn * DIM;
        int sidx = l * DIM * DIM + kk * DIM + nn;
        W1T[i] = f2b(W1[sidx]);
        W2T[i] = f2b(W2[sidx]);
    }
}

__global__ void conv_x(const float* __restrict__ x, unsigned short* __restrict__ xb, int n4) {
    int i = blockIdx.x * blockDim.x + threadIdx.x;
    if (i < n4) {
        float4 v = ((const float4*)x)[i];
        unsigned lo = pack2(v.x, v.y);
        unsigned hi = pack2(v.z, v.w);
        ((uint2*)xb)[i] = make_uint2(lo, hi);
    }
}

// ---------------- gather0: weighted SimpleConv for SUPERNODES ONLY; copy otherwise ----------------
// REVERSED index order (LPT): heavy sn nodes (top of perm) dispatch first; light copy
// nodes fill the scheduling tail.

__global__ __launch_bounds__(256) void gather0(const unsigned short* __restrict__ xb,
                                               const int* __restrict__ off, const int* __restrict__ deg,
                                               const unsigned* __restrict__ csr4,
                                               const int* __restrict__ snmask,
                                               const int* __restrict__ perm,
                                               unsigned short* __restrict__ X, int n) {
    int wave = (blockIdx.x * blockDim.x + threadIdx.x) >> 6;
    int lane = threadIdx.x & 63;
    int q    = lane >> 4;
    int l16  = lane & 15;
    int fidx = wave * 4 + q;
    bool valid = fidx < n;
    int idx  = n - 1 - (valid ? fidx : 0);   // reversed: heaviest first
    int node = perm[idx];
    int base = off[node];
    bool sn  = valid && snmask[node];
    int dg   = sn ? deg[node] : 0;   // non-supernode: skip gather entirely

    float acc[8];
#pragma unroll
    for (int i = 0; i < 8; ++i) acc[i] = 0.f;

    int j = 0;
    for (; j + 8 <= dg; j += 8) {
        unsigned cc[8];
#pragma unroll
        for (int u = 0; u < 8; ++u) cc[u] = csr4[base + j + u];
        bf16x8 vv[8];
#pragma unroll
        for (int u = 0; u < 8; ++u)
            vv[u] = *(const bf16x8*)&xb[(long)(cc[u] & 0xffffu) * DIM + l16 * 8];
#pragma unroll
        for (int u = 0; u < 8; ++u) {
            float w = __half2float(__ushort_as_half((unsigned short)(cc[u] >> 16)));
#pragma unroll
            for (int i = 0; i < 8; ++i) acc[i] = fmaf(w, b2f(vv[u][i]), acc[i]);
        }
    }
    for (; j + 4 <= dg; j += 4) {
        unsigned cc[4];
#pragma unroll
        for (int u = 0; u < 4; ++u) cc[u] = csr4[base + j + u];
        bf16x8 vv[4];
#pragma unroll
        for (int u = 0; u < 4; ++u)
            vv[u] = *(const bf16x8*)&xb[(long)(cc[u] & 0xffffu) * DIM + l16 * 8];
#pragma unroll
        for (int u = 0; u < 4; ++u) {
            float w = __half2float(__ushort_as_half((unsigned short)(cc[u] >> 16)));
#pragma unroll
            for (int i = 0; i < 8; ++i) acc[i] = fmaf(w, b2f(vv[u][i]), acc[i]);
        }
    }
    for (; j < dg; ++j) {
        unsigned c = csr4[base + j];
        float w = __half2float(__ushort_as_half((unsigned short)(c >> 16)));
        bf16x8 v = *(const bf16x8*)&xb[(long)(c & 0xffffu) * DIM + l16 * 8];
#pragma unroll
        for (int i = 0; i < 8; ++i) acc[i] = fmaf(w, b2f(v[i]), acc[i]);
    }

    if (valid) {
        bf16x8 res;
        if (sn) {
#pragma unroll
            for (int i = 0; i < 8; ++i) res[i] = (short)f2b(acc[i]);
        } else {
            res = *(const bf16x8*)&xb[(long)node * DIM + l16 * 8];
        }
        *(bf16x8*)&X[(long)node * DIM + l16 * 8] = res;
    }
}

// ---------------- fused GIN layer: gather(LDS) -> GEMM1 -> GEMM2 ----------------
// 512 threads = 8 waves, 64 rows/block, contiguous-descending block mapping (LPT).
#define HPITCH 136   // bf16 elems; 272B rows: 16B-aligned, 2-way LDS aliasing only

__global__ __launch_bounds__(512) void gin_layer(const unsigned short* __restrict__ Xin,
                                                 unsigned short* __restrict__ Xout,
                                                 const int* __restrict__ off, const int* __restrict__ deg,
                                                 const unsigned* __restrict__ csr4,
                                                 const int* __restrict__ perm,
                                                 const unsigned short* __restrict__ W1T,
                                                 const unsigned short* __restrict__ W2T,
                                                 const float* __restrict__ colA, const float* __restrict__ colB,
                                                 const float* __restrict__ b2, int n) {
    __shared__ unsigned short h_in[64 * HPITCH];
    __shared__ unsigned short h_t[64 * HPITCH];
    int t    = threadIdx.x;
    int wid  = t >> 6;
    int lane = t & 63;
    int q    = lane >> 4;
    int l16  = lane & 15;
    int lm   = lane & 15;
    int lk   = (lane >> 4) * 8;
    int wr   = wid >> 2;          // 0..1
    int wc   = wid & 3;           // 0..3
    int c0   = wc * 32;
    int nb   = gridDim.x;
    int row0 = (nb - 1 - (int)blockIdx.x) * 64;   // descending-contiguous

    // ---- W1 B-fragments first: weight fetch overlaps gather latency ----
    bf16x8 b1[2][4];
#pragma unroll
    for (int cs = 0; cs < 2; ++cs)
#pragma unroll
        for (int ks = 0; ks < 4; ++ks) {
            int col = c0 + cs * 16 + lm;
            b1[cs][ks] = *(const bf16x8*)&W1T[col * DIM + ks * 32 + lk];
        }

    // ---- gather phase: GIN eps=0 agg into h_in (sorted-uniform quarter-waves) ----
#pragma unroll
    for (int rnd = 0; rnd < 2; ++rnd) {
        int lrow = wid * 8 + rnd * 4 + q;
        int idx  = row0 + lrow;
        bool valid = idx < n;
        int node = perm[valid ? idx : (n - 1)];
        int base = off[node];
        int dg   = valid ? deg[node] : 0;

        float acc[8];
        {
            bf16x8 self = *(const bf16x8*)&Xin[(long)node * DIM + l16 * 8];
#pragma unroll
            for (int i = 0; i < 8; ++i) acc[i] = b2f(self[i]);
        }
        int j = 0;
        for (; j + 8 <= dg; j += 8) {
            unsigned ee[8];
#pragma unroll
            for (int u = 0; u < 8; ++u) ee[u] = csr4[base + j + u];
            bf16x8 vv[8];
#pragma unroll
            for (int u = 0; u < 8; ++u)
                vv[u] = *(const bf16x8*)&Xin[(long)(ee[u] & 0xffffu) * DIM + l16 * 8];
#pragma unroll
            for (int u = 0; u < 8; ++u)
#pragma unroll
                for (int i = 0; i < 8; ++i) acc[i] += b2f(vv[u][i]);
        }
        for (; j + 4 <= dg; j += 4) {
            unsigned ee[4];
#pragma unroll
            for (int u = 0; u < 4; ++u) ee[u] = csr4[base + j + u];
            bf16x8 vv[4];
#pragma unroll
            for (int u = 0; u < 4; ++u)
                vv[u] = *(const bf16x8*)&Xin[(long)(ee[u] & 0xffffu) * DIM + l16 * 8];
#pragma unroll
            for (int u = 0; u < 4; ++u)
#pragma unroll
                for (int i = 0; i < 8; ++i) acc[i] += b2f(vv[u][i]);
        }
        for (; j < dg; ++j) {
            unsigned e = csr4[base + j];
            bf16x8 v = *(const bf16x8*)&Xin[(long)(e & 0xffffu) * DIM + l16 * 8];
#pragma unroll
            for (int i = 0; i < 8; ++i) acc[i] += b2f(v[i]);
        }
        bf16x8 r;
#pragma unroll
        for (int i = 0; i < 8; ++i) r[i] = valid ? (short)f2b(acc[i]) : (short)0;
        *(bf16x8*)&h_in[lrow * HPITCH + l16 * 8] = r;
    }
    __syncthreads();

    // ---- GEMM1 ----
    bf16x8 a[2][4];
#pragma unroll
    for (int rs = 0; rs < 2; ++rs)
#pragma unroll
        for (int ks = 0; ks < 4; ++ks)
            a[rs][ks] = *(const bf16x8*)&h_in[(wr * 32 + rs * 16 + lm) * HPITCH + ks * 32 + lk];

    f32x4 acc[2][2];
    f32x4 z = {0.f, 0.f, 0.f, 0.f};
#pragma unroll
    for (int rs = 0; rs < 2; ++rs)
#pragma unroll
        for (int cs = 0; cs < 2; ++cs) acc[rs][cs] = z;

#pragma unroll
    for (int ks = 0; ks < 4; ++ks)
#pragma unroll
        for (int rs = 0; rs < 2; ++rs)
#pragma unroll
            for (int cs = 0; cs < 2; ++cs)
                acc[rs][cs] = __builtin_amdgcn_mfma_f32_16x16x32_bf16(a[rs][ks], b1[cs][ks], acc[rs][cs], 0, 0, 0);

    // ---- epilogue 1: affine(BN)+ReLU -> h_t ----
#pragma unroll
    for (int rs = 0; rs < 2; ++rs)
#pragma unroll
        for (int cs = 0; cs < 2; ++cs) {
            int colv = c0 + cs * 16 + lm;
            float cA = colA[colv], cB = colB[colv];
            int rbase = wr * 32 + rs * 16 + (lane >> 4) * 4;
            f32x4 av = acc[rs][cs];
#pragma unroll
            for (int v = 0; v < 4; ++v) {
                float h = fmaxf(fmaf(av[v], cA, cB), 0.f);
                h_t[(rbase + v) * HPITCH + colv] = f2b(h);
            }
        }
    __syncthreads();

    // ---- GEMM2 ----
    bf16x8 a2[2][4];
#pragma unroll
    for (int rs = 0; rs < 2; ++rs)
#pragma unroll
        for (int ks = 0; ks < 4; ++ks)
            a2[rs][ks] = *(const bf16x8*)&h_t[(wr * 32 + rs * 16 + lm) * HPITCH + ks * 32 + lk];

    bf16x8 b2f_[2][4];
#pragma unroll
    for (int cs = 0; cs < 2; ++cs)
#pragma unroll
        for (int ks = 0; ks < 4; ++ks) {
            int col = c0 + cs * 16 + lm;
            b2f_[cs][ks] = *(const bf16x8*)&W2T[col * DIM + ks * 32 + lk];
        }

#pragma unroll
    for (int rs = 0; rs < 2; ++rs)
#pragma unroll
        for (int cs = 0; cs < 2; ++cs) acc[rs][cs] = z;

#pragma unroll
    for (int ks = 0; ks < 4; ++ks)
#pragma unroll
        for (int rs = 0; rs < 2; ++rs)
#pragma unroll
            for (int cs = 0; cs < 2; ++cs)
                acc[rs][cs] = __builtin_amdgcn_mfma_f32_16x16x32_bf16(a2[rs][ks], b2f_[cs][ks], acc[rs][cs], 0, 0, 0);

    __syncthreads();

    // ---- epilogue 2: +bias, ReLU -> h_t ----
#pragma unroll
    for (int rs = 0; rs < 2; ++rs)
#pragma unroll
        for (int cs = 0; cs < 2; ++cs) {
            int colv = c0 + cs * 16 + lm;
            float bb = b2[colv];
            int rbase = wr * 32 + rs * 16 + (lane >> 4) * 4;
            f32x4 av = acc[rs][cs];
#pragma unroll
            for (int v = 0; v < 4; ++v) {
                float h = fmaxf(av[v] + bb, 0.f);
                h_t[(rbase + v) * HPITCH + colv] = f2b(h);
            }
        }
    __syncthreads();

    // ---- copy-out: row -> descending-contiguous idx -> Xout[perm[idx]] ----
    {
        int row = t >> 3;
        int ch  = (t & 7) * 16;
        int idx = row0 + row;
        if (idx < n) {
            int node = perm[idx];
            *(bf16x8*)&Xout[(long)node * DIM + ch]     = *(const bf16x8*)&h_t[row * HPITCH + ch];
            *(bf16x8*)&Xout[(long)node * DIM + ch + 8] = *(const bf16x8*)&h_t[row * HPITCH + ch + 8];
        }
    }
}

// ---------------- pool (batch sorted -> run-accumulate) ----------------
// Round-14 lesson: 128-row serial loop per block = latency-bound (40us, 1% VALU).
// Now 32 rows/block (1563 blocks), 2x16-row strips, 4x unrolled independent loads.

__global__ __launch_bounds__(256) void pool_kernel(const unsigned short* __restrict__ X,
                                                   const int* __restrict__ batch,
                                                   float* __restrict__ POOL, int n) {
    int t    = threadIdx.x;
    int half = t >> 7;           // 0..1
    int c    = t & 127;          // channel
    int n0 = blockIdx.x * 32 + half * 16;
    if (n0 >= n) return;
    int n1 = n0 + 16; if (n1 > n) n1 = n;
    int gcur = batch[n0];
    float acc = 0.f;
    int i = n0;
    for (; i + 4 <= n1; i += 4) {
        int g0 = batch[i], g1 = batch[i + 1], g2 = batch[i + 2], g3 = batch[i + 3];
        float v0 = b2f((short)X[(long)(i    ) * DIM + c]);
        float v1 = b2f((short)X[(long)(i + 1) * DIM + c]);
        float v2 = b2f((short)X[(long)(i + 2) * DIM + c]);
        float v3 = b2f((short)X[(long)(i + 3) * DIM + c]);
        if (g0 != gcur) { atomicAdd(&POOL[(long)gcur * DIM + c], acc); acc = 0.f; gcur = g0; }
        acc += v0;
        if (g1 != gcur) { atomicAdd(&POOL[(long)gcur * DIM + c], acc); acc = 0.f; gcur = g1; }
        acc += v1;
        if (g2 != gcur) { atomicAdd(&POOL[(long)gcur * DIM + c], acc); acc = 0.f; gcur = g2; }
        acc += v2;
        if (g3 != gcur) { atomicAdd(&POOL[(long)gcur * DIM + c], acc); acc = 0.f; gcur = g3; }
        acc += v3;
    }
    for (; i < n1; ++i) {
        int g = batch[i];
        float v = b2f((short)X[(long)i * DIM + c]);
        if (g != gcur) { atomicAdd(&POOL[(long)gcur * DIM + c], acc); acc = 0.f; gcur = g; }
        acc += v;
    }
    atomicAdd(&POOL[(long)gcur * DIM + c], acc);
}

// ---------------- final head ----------------

__global__ __launch_bounds__(128) void final_mlp(const float* __restrict__ POOL,
                                                 const float* __restrict__ Wf1, const float* __restrict__ bf1,
                                                 const float* __restrict__ Wf2, const float* __restrict__ bf2,
                                                 float* __restrict__ out) {
    int g = blockIdx.x;
    int t = threadIdx.x;
    __shared__ float p[128];
    __shared__ float h[128];
    p[t] = POOL[(long)g * DIM + t];
    __syncthreads();
    float acc = bf1[t];
#pragma unroll 8
    for (int k = 0; k < DIM; ++k) acc = fmaf(p[k], Wf1[k * DIM + t], acc);
    h[t] = fmaxf(acc, 0.f);
    __syncthreads();
    if (t < NCLS) {
        float acc2 = bf2[t];
#pragma unroll 8
        for (int k = 0; k < DIM; ++k) acc2 = fmaf(h[k], Wf2[k * NCLS + t], acc2);
        out[(long)g * NCLS + t] = acc2;
    }
}

// ---------------- launch ----------------

extern "C" void kernel_launch(void* const* d_in, const int* in_sizes, int n_in,
                              void* d_out, int out_size, void* d_ws, size_t ws_size,
                              hipStream_t stream) {
    const float* x      = (const float*)d_in[0];
    const int*   ei     = (const int*)d_in[1];
    const int*   snmask = (const int*)d_in[2];
    const float* emask  = (const float*)d_in[3];
    const int*   batch  = (const int*)d_in[4];
    const float* Ws1    = (const float*)d_in[5];
    const float* bs1    = (const float*)d_in[6];
    const float* gamma  = (const float*)d_in[7];
    const float* beta   = (const float*)d_in[8];
    const float* mean   = (const float*)d_in[9];
    const float* var    = (const float*)d_in[10];
    const float* Ws2    = (const float*)d_in[11];
    const float* bs2    = (const float*)d_in[12];
    const float* Wf1    = (const float*)d_in[13];
    const float* bf1    = (const float*)d_in[14];
    const float* Wf2    = (const float*)d_in[15];
    const float* bf2    = (const float*)d_in[16];
    float* out = (float*)d_out;

    const int* srcp = ei;
    const int* dstp = ei + NEDGES;

    char* ws = (char*)d_ws;
    size_t o = 0;
    auto alloc = [&](size_t bytes) -> void* {
        void* p = ws + o;
        o = (o + bytes + 255) & ~(size_t)255;
        return p;
    };
    unsigned short* XB  = (unsigned short*)alloc((size_t)NNODES * DIM * 2);
    unsigned short* X   = (unsigned short*)alloc((size_t)NNODES * DIM * 2);
    unsigned short* H   = (unsigned short*)alloc((size_t)NNODES * DIM * 2);
    int*   deg     = (int*)alloc((size_t)NNODES * 4);
    int*   off     = (int*)alloc((size_t)NNODES * 4);
    int*   rank    = (int*)alloc((size_t)NEDGES * 4);
    int*   part    = (int*)alloc((size_t)NSB * 4);
    unsigned* csr4 = (unsigned*)alloc((size_t)NEDGES * 4);
    int*   blockHist = (int*)alloc((size_t)NBINS * NSB * 4);
    int*   perm    = (int*)alloc((size_t)NNODES * 4);
    float* colA    = (float*)alloc((size_t)NLAYERS * DIM * 4);
    float* colB    = (float*)alloc((size_t)NLAYERS * DIM * 4);
    unsigned short* W1T = (unsigned short*)alloc((size_t)NLAYERS * DIM * DIM * 2);
    unsigned short* W2T = (unsigned short*)alloc((size_t)NLAYERS * DIM * DIM * 2);
    float* POOL    = (float*)alloc((size_t)NGRAPH * DIM * 4);

    // deg: 12500 int4; POOL: 8192 int4
    zero_bufs<<<(12500 + 255) / 256, 256, 0, stream>>>((int4*)deg, 12500, (int4*)POOL, 8192);

    count_deg<<<(NEDGES + 255) / 256, 256, 0, stream>>>(dstp, deg, rank, NEDGES);
    partial_sum<<<NSB, SCAN_BLK, 0, stream>>>(deg, part, NNODES);
    scan_partials<<<1, 256, 0, stream>>>(part, NSB);
    emit_offsets<<<NSB, SCAN_BLK, 0, stream>>>(deg, part, off, NNODES);
    place_csr<<<(NEDGES + 255) / 256, 256, 0, stream>>>(srcp, dstp, emask, off, rank, csr4, NEDGES);
    hist_block<<<NSB, 256, 0, stream>>>(deg, snmask, blockHist, NNODES);
    scan_matrix<<<1, 1024, 0, stream>>>(blockHist, NBINS * NSB);
    place_block<<<NSB, 256, 0, stream>>>(deg, snmask, blockHist, perm, NNODES);
    prep_bn<<<(NLAYERS * DIM + 255) / 256, 256, 0, stream>>>(gamma, beta, mean, var, bs1, colA, colB, NLAYERS * DIM);
    prep_wt<<<(NLAYERS * DIM * DIM + 255) / 256, 256, 0, stream>>>(Ws1, Ws2, W1T, W2T, NLAYERS * DIM * DIM);
    conv_x<<<(NNODES * DIM / 4 + 255) / 256, 256, 0, stream>>>(x, XB, NNODES * DIM / 4);

    const int nWaves = (NNODES + 3) / 4;
    const int gatherBlocks = (nWaves * 64 + 255) / 256;
    gather0<<<gatherBlocks, 256, 0, stream>>>(XB, off, deg, csr4, snmask, perm, X, NNODES);

    // ping-pong: X -> H -> X -> H
    const unsigned short* bufs[4] = {X, H, X, H};
    const int layerBlocks = (NNODES + 63) / 64;
    for (int l = 0; l < NLAYERS; ++l) {
        gin_layer<<<layerBlocks, 512, 0, stream>>>((const unsigned short*)bufs[l],
                                                   (unsigned short*)bufs[l + 1],
                                                   off, deg, csr4, perm,
                                                   W1T + (size_t)l * DIM * DIM,
                                                   W2T + (size_t)l * DIM * DIM,
                                                   colA + (size_t)l * DIM,
                                                   colB + (size_t)l * DIM,
                                                   bs2 + (size_t)l * DIM, NNODES);
    }

    pool_kernel<<<(NNODES + 31) / 32, 256, 0, stream>>>(H, batch, POOL, NNODES);
    final_mlp<<<NGRAPH, 128, 0, stream>>>(POOL, Wf1, bf1, Wf2, bf2, out);
}